// Round 1
// baseline (1069.633 us; speedup 1.0000x reference)
//
#include <hip/hip_runtime.h>

#define N_NODES 50000
#define F0 256
#define F1 128
#define F2 64
#define BN_EPS 1e-5f

// ---------------- CSR build ----------------
__global__ void count_dst(const int* __restrict__ dst, int* __restrict__ counts, int E) {
  int e = blockIdx.x * blockDim.x + threadIdx.x;
  if (e < E) atomicAdd(&counts[dst[e]], 1);
}

__global__ void compute_dinv(const int* __restrict__ counts, float* __restrict__ dinv) {
  int i = blockIdx.x * blockDim.x + threadIdx.x;
  if (i < N_NODES) dinv[i] = rsqrtf((float)counts[i] + 1.0f);
}

__global__ __launch_bounds__(1024) void scan_offsets(const int* __restrict__ counts,
                                                     int* __restrict__ offs) {
  __shared__ int s_wsum[16];
  __shared__ int s_carry, s_total;
  int tid = threadIdx.x;
  int lane = tid & 63, wid = tid >> 6;
  if (tid == 0) s_carry = 0;
  __syncthreads();
  for (int base = 0; base < N_NODES; base += 1024) {
    int i = base + tid;
    int v = (i < N_NODES) ? counts[i] : 0;
    int incl = v;
#pragma unroll
    for (int d = 1; d < 64; d <<= 1) {
      int t = __shfl_up(incl, d);
      if (lane >= d) incl += t;
    }
    if (lane == 63) s_wsum[wid] = incl;
    __syncthreads();
    if (tid == 0) {
      int run = 0;
      for (int j = 0; j < 16; j++) { int t = s_wsum[j]; s_wsum[j] = run; run += t; }
      s_total = run;
    }
    __syncthreads();
    if (i < N_NODES) offs[i] = s_carry + s_wsum[wid] + incl - v;
    __syncthreads();
    if (tid == 0) s_carry += s_total;
    __syncthreads();
  }
  if (tid == 0) offs[N_NODES] = s_carry;
}

__global__ void fill_csr(const int* __restrict__ src, const int* __restrict__ dst,
                         const int* __restrict__ offs, int* __restrict__ cursor,
                         const float* __restrict__ dinv,
                         int* __restrict__ csr_src, float* __restrict__ csr_w, int E) {
  int e = blockIdx.x * blockDim.x + threadIdx.x;
  if (e < E) {
    int s = src[e], d = dst[e];
    int p = offs[d] + atomicAdd(&cursor[d], 1);
    csr_src[p] = s;
    csr_w[p] = dinv[s] * dinv[d];
  }
}

// ---------------- fp32 tiled GEMM: C[M,Nout] = A[M,K] @ W[K,Nout] + bias ----------------
// BM=128, BN=64, BK=16; 256 threads; each thread 8 rows x 4 cols.
__global__ __launch_bounds__(256) void gemm_bias(const float* __restrict__ A,
                                                 const float* __restrict__ W,
                                                 const float* __restrict__ bias,
                                                 float* __restrict__ C,
                                                 int M, int K, int Nout) {
  __shared__ float As[16][128];  // [k][m] transposed
  __shared__ float Bs[16][64];   // [k][n]
  int tid = threadIdx.x;
  int tx = tid & 15;   // col group (0..15) -> 4 cols each
  int ty = tid >> 4;   // row group (0..15) -> 8 rows each
  int m0 = blockIdx.x * 128;
  int n0 = blockIdx.y * 64;
  float acc[8][4] = {};

  for (int k0 = 0; k0 < K; k0 += 16) {
    // A tile: 128 rows x 16 k = 512 float4, 2 per thread
#pragma unroll
    for (int i = 0; i < 2; i++) {
      int l4 = tid + i * 256;
      int row = l4 >> 2;
      int cg = (l4 & 3) * 4;
      int grow = m0 + row;
      float4 v = make_float4(0.f, 0.f, 0.f, 0.f);
      if (grow < M) v = *(const float4*)(A + (size_t)grow * K + k0 + cg);
      As[cg + 0][row] = v.x;
      As[cg + 1][row] = v.y;
      As[cg + 2][row] = v.z;
      As[cg + 3][row] = v.w;
    }
    // B tile: 16 k x 64 n = 256 float4, 1 per thread
    {
      int r = tid >> 4;
      int cg = (tid & 15) * 4;
      float4 v = *(const float4*)(W + (size_t)(k0 + r) * Nout + n0 + cg);
      *(float4*)&Bs[r][cg] = v;
    }
    __syncthreads();
#pragma unroll
    for (int k = 0; k < 16; k++) {
      float4 b = *(float4*)&Bs[k][tx * 4];
      float4 a0 = *(const float4*)&As[k][ty * 8];
      float4 a1 = *(const float4*)&As[k][ty * 8 + 4];
      float a[8] = {a0.x, a0.y, a0.z, a0.w, a1.x, a1.y, a1.z, a1.w};
#pragma unroll
      for (int i = 0; i < 8; i++) {
        acc[i][0] = fmaf(a[i], b.x, acc[i][0]);
        acc[i][1] = fmaf(a[i], b.y, acc[i][1]);
        acc[i][2] = fmaf(a[i], b.z, acc[i][2]);
        acc[i][3] = fmaf(a[i], b.w, acc[i][3]);
      }
    }
    __syncthreads();
  }

  float4 bv = *(const float4*)(bias + n0 + tx * 4);
#pragma unroll
  for (int i = 0; i < 8; i++) {
    int grow = m0 + ty * 8 + i;
    if (grow < M) {
      float4 o;
      o.x = acc[i][0] + bv.x;
      o.y = acc[i][1] + bv.y;
      o.z = acc[i][2] + bv.z;
      o.w = acc[i][3] + bv.w;
      *(float4*)(C + (size_t)grow * Nout + n0 + tx * 4) = o;
    }
  }
}

// ---------------- aggregation + self-loop + relu + BN stats ----------------
// stat[0..256) = per-channel sum, stat[256..512) = per-channel sumsq
template <int F>
__global__ __launch_bounds__(256) void agg_relu_stats(
    const float* __restrict__ hlin, const int* __restrict__ offs,
    const int* __restrict__ csr_src, const float* __restrict__ csr_w,
    const float* __restrict__ dinv, float* __restrict__ out,
    float* __restrict__ stat) {
  constexpr int NPB = 256 / F;
  int tid = threadIdx.x;
  int c = tid % F;
  int sub = tid / F;
  float lsum = 0.f, lsq = 0.f;
  for (int node = blockIdx.x * NPB + sub; node < N_NODES; node += gridDim.x * NPB) {
    int e0 = offs[node], e1 = offs[node + 1];
    float acc = 0.f;
#pragma unroll 4
    for (int e = e0; e < e1; e++) {
      acc = fmaf(hlin[(size_t)csr_src[e] * F + c], csr_w[e], acc);
    }
    float di = dinv[node];
    acc = fmaf(hlin[(size_t)node * F + c], di * di, acc);
    float a = fmaxf(acc, 0.f);
    out[(size_t)node * F + c] = a;
    lsum += a;
    lsq = fmaf(a, a, lsq);
  }
  __shared__ float red[256];
  red[tid] = lsum;
  __syncthreads();
  if (tid < F) {
    float s = red[tid];
    for (int j = tid + F; j < 256; j += F) s += red[j];
    atomicAdd(&stat[tid], s);
  }
  __syncthreads();
  red[tid] = lsq;
  __syncthreads();
  if (tid < F) {
    float s = red[tid];
    for (int j = tid + F; j < 256; j += F) s += red[j];
    atomicAdd(&stat[256 + tid], s);
  }
}

// ---------------- BN finalize: per-channel scale/shift ----------------
__global__ void bn_finalize(const float* __restrict__ stat, const float* __restrict__ g,
                            const float* __restrict__ bb, float* __restrict__ scale,
                            float* __restrict__ shift, int F) {
  int c = threadIdx.x;
  if (c < F) {
    const float invN = 1.0f / (float)N_NODES;
    float mean = stat[c] * invN;
    float var = stat[256 + c] * invN - mean * mean;
    var = fmaxf(var, 0.f);
    float inv = rsqrtf(var + BN_EPS);
    float sc = g[c] * inv;
    scale[c] = sc;
    shift[c] = bb[c] - mean * sc;
  }
}

// ---------------- BN apply (vectorized, optional relu) ----------------
template <int F, bool RELU>
__global__ __launch_bounds__(256) void bn_apply(const float* __restrict__ a,
                                                const float* __restrict__ scale,
                                                const float* __restrict__ shift,
                                                float* __restrict__ out) {
  constexpr int C4 = F / 4;
  const int total = N_NODES * C4;
  for (int idx = blockIdx.x * blockDim.x + threadIdx.x; idx < total;
       idx += gridDim.x * blockDim.x) {
    int c4 = idx % C4;
    float4 v = ((const float4*)a)[idx];
    float4 s = ((const float4*)scale)[c4];
    float4 sh = ((const float4*)shift)[c4];
    float4 o;
    o.x = fmaf(v.x, s.x, sh.x);
    o.y = fmaf(v.y, s.y, sh.y);
    o.z = fmaf(v.z, s.z, sh.z);
    o.w = fmaf(v.w, s.w, sh.w);
    if (RELU) {
      o.x = fmaxf(o.x, 0.f);
      o.y = fmaxf(o.y, 0.f);
      o.z = fmaxf(o.z, 0.f);
      o.w = fmaxf(o.w, 0.f);
    }
    ((float4*)out)[idx] = o;
  }
}

extern "C" void kernel_launch(void* const* d_in, const int* in_sizes, int n_in,
                              void* d_out, int out_size, void* d_ws, size_t ws_size,
                              hipStream_t stream) {
  const float* x = (const float*)d_in[0];
  const int* ei = (const int*)d_in[1];
  const int E = in_sizes[1] / 2;
  const int* src = ei;
  const int* dst = ei + E;
  const float* We1 = (const float*)d_in[2];  const float* be1 = (const float*)d_in[3];
  const float* g1  = (const float*)d_in[4];  const float* bb1 = (const float*)d_in[5];
  const float* We2 = (const float*)d_in[6];  const float* be2 = (const float*)d_in[7];
  const float* g2  = (const float*)d_in[8];  const float* bb2 = (const float*)d_in[9];
  const float* Wd1 = (const float*)d_in[10]; const float* bd1 = (const float*)d_in[11];
  const float* g3  = (const float*)d_in[12]; const float* bb3 = (const float*)d_in[13];
  const float* Wd2 = (const float*)d_in[14]; const float* bd2 = (const float*)d_in[15];
  const float* g4  = (const float*)d_in[16]; const float* bb4 = (const float*)d_in[17];

  float* out = (float*)d_out;
  char* ws = (char*)d_ws;
  // workspace layout (bytes)
  float* bufA   = (float*)(ws + 0);            // 50000*256*4 = 51,200,000
  float* bufB   = (float*)(ws + 51200000);     // 51,200,000
  int*   csrS   = (int*)(ws + 102400000);      // E*4 = 3,200,000
  float* csrW   = (float*)(ws + 105600000);    // 3,200,000
  int*   counts = (int*)(ws + 108800000);      // 200,000
  int*   cursor = (int*)(ws + 109000000);      // 200,000 (contiguous w/ counts)
  int*   offs   = (int*)(ws + 109200000);      // 200,004
  float* dinv   = (float*)(ws + 109400064);    // 200,000
  float* stat   = (float*)(ws + 109600064);    // 2,048
  float* scale  = (float*)(ws + 109602112);    // 1,024
  float* shift  = (float*)(ws + 109603136);    // 1,024
  if (ws_size < 109604160) return;

  float* enc1 = out + (size_t)N_NODES * F0;
  float* enc2 = enc1 + (size_t)N_NODES * F1;

  const int EB = (E + 255) / 256;

  // CSR build + degree normalization
  hipMemsetAsync(counts, 0, 2 * N_NODES * sizeof(int), stream);
  count_dst<<<EB, 256, 0, stream>>>(dst, counts, E);
  compute_dinv<<<(N_NODES + 255) / 256, 256, 0, stream>>>(counts, dinv);
  scan_offsets<<<1, 1024, 0, stream>>>(counts, offs);
  fill_csr<<<EB, 256, 0, stream>>>(src, dst, offs, cursor, dinv, csrS, csrW, E);

  const int MB = (N_NODES + 127) / 128;  // 391

  // ---- Layer 1: F0 -> F1, relu(BN) -> enc1 ----
  gemm_bias<<<dim3(MB, F1 / 64), 256, 0, stream>>>(x, We1, be1, bufA, N_NODES, F0, F1);
  hipMemsetAsync(stat, 0, 512 * sizeof(float), stream);
  agg_relu_stats<F1><<<768, 256, 0, stream>>>(bufA, offs, csrS, csrW, dinv, bufB, stat);
  bn_finalize<<<1, 256, 0, stream>>>(stat, g1, bb1, scale, shift, F1);
  bn_apply<F1, true><<<1280, 256, 0, stream>>>(bufB, scale, shift, enc1);

  // ---- Layer 2: F1 -> F2, BN (no relu) -> enc2 ----
  gemm_bias<<<dim3(MB, F2 / 64), 256, 0, stream>>>(enc1, We2, be2, bufA, N_NODES, F1, F2);
  hipMemsetAsync(stat, 0, 512 * sizeof(float), stream);
  agg_relu_stats<F2><<<768, 256, 0, stream>>>(bufA, offs, csrS, csrW, dinv, bufB, stat);
  bn_finalize<<<1, 256, 0, stream>>>(stat, g2, bb2, scale, shift, F2);
  bn_apply<F2, false><<<1280, 256, 0, stream>>>(bufB, scale, shift, enc2);

  // ---- Layer 3: F2 -> F1, relu(BN) -> bufB (in-place) ----
  gemm_bias<<<dim3(MB, F1 / 64), 256, 0, stream>>>(enc2, Wd1, bd1, bufA, N_NODES, F2, F1);
  hipMemsetAsync(stat, 0, 512 * sizeof(float), stream);
  agg_relu_stats<F1><<<768, 256, 0, stream>>>(bufA, offs, csrS, csrW, dinv, bufB, stat);
  bn_finalize<<<1, 256, 0, stream>>>(stat, g3, bb3, scale, shift, F1);
  bn_apply<F1, true><<<1280, 256, 0, stream>>>(bufB, scale, shift, bufB);

  // ---- Layer 4: F1 -> F0, BN (no relu) -> out ----
  gemm_bias<<<dim3(MB, F0 / 64), 256, 0, stream>>>(bufB, Wd2, bd2, bufA, N_NODES, F1, F0);
  hipMemsetAsync(stat, 0, 512 * sizeof(float), stream);
  agg_relu_stats<F0><<<768, 256, 0, stream>>>(bufA, offs, csrS, csrW, dinv, bufB, stat);
  bn_finalize<<<1, 256, 0, stream>>>(stat, g4, bb4, scale, shift, F0);
  bn_apply<F0, false><<<1280, 256, 0, stream>>>(bufB, scale, shift, out);
}

// Round 2
// 1024.261 us; speedup vs baseline: 1.0443x; 1.0443x over previous
//
#include <hip/hip_runtime.h>

#define N_NODES 50000
#define F0 256
#define F1 128
#define F2 64
#define BN_EPS 1e-5f

// ---------------- CSR build ----------------
__global__ void count_dst(const int* __restrict__ dst, int* __restrict__ counts, int E) {
  int e = blockIdx.x * blockDim.x + threadIdx.x;
  if (e < E) atomicAdd(&counts[dst[e]], 1);
}

__global__ void compute_dinv(const int* __restrict__ counts, float* __restrict__ dinv) {
  int i = blockIdx.x * blockDim.x + threadIdx.x;
  if (i < N_NODES) dinv[i] = rsqrtf((float)counts[i] + 1.0f);
}

__global__ __launch_bounds__(1024) void scan_offsets(const int* __restrict__ counts,
                                                     int* __restrict__ offs) {
  __shared__ int s_wsum[16];
  __shared__ int s_carry, s_total;
  int tid = threadIdx.x;
  int lane = tid & 63, wid = tid >> 6;
  if (tid == 0) s_carry = 0;
  __syncthreads();
  for (int base = 0; base < N_NODES; base += 1024) {
    int i = base + tid;
    int v = (i < N_NODES) ? counts[i] : 0;
    int incl = v;
#pragma unroll
    for (int d = 1; d < 64; d <<= 1) {
      int t = __shfl_up(incl, d);
      if (lane >= d) incl += t;
    }
    if (lane == 63) s_wsum[wid] = incl;
    __syncthreads();
    if (tid == 0) {
      int run = 0;
      for (int j = 0; j < 16; j++) { int t = s_wsum[j]; s_wsum[j] = run; run += t; }
      s_total = run;
    }
    __syncthreads();
    if (i < N_NODES) offs[i] = s_carry + s_wsum[wid] + incl - v;
    __syncthreads();
    if (tid == 0) s_carry += s_total;
    __syncthreads();
  }
  if (tid == 0) offs[N_NODES] = s_carry;
}

__global__ void fill_csr(const int* __restrict__ src, const int* __restrict__ dst,
                         const int* __restrict__ offs, int* __restrict__ cursor,
                         const float* __restrict__ dinv,
                         int* __restrict__ csr_src, float* __restrict__ csr_w, int E) {
  int e = blockIdx.x * blockDim.x + threadIdx.x;
  if (e < E) {
    int s = src[e], d = dst[e];
    int p = offs[d] + atomicAdd(&cursor[d], 1);
    csr_src[p] = s;
    csr_w[p] = dinv[s] * dinv[d];
  }
}

// rowsum[i] = sum of incoming edge weights + self-loop weight (graph constant)
__global__ void compute_rowsum(const int* __restrict__ offs, const float* __restrict__ csr_w,
                               const float* __restrict__ dinv, float* __restrict__ rowsum) {
  int i = blockIdx.x * blockDim.x + threadIdx.x;
  if (i < N_NODES) {
    float s = dinv[i] * dinv[i];
    int e1 = offs[i + 1];
    for (int e = offs[i]; e < e1; e++) s += csr_w[e];
    rowsum[i] = s;
  }
}

// ---------------- fp32 tiled GEMM: C = A @ W + bias (L1, L2) ----------------
__global__ __launch_bounds__(256) void gemm_bias(const float* __restrict__ A,
                                                 const float* __restrict__ W,
                                                 const float* __restrict__ bias,
                                                 float* __restrict__ C,
                                                 int M, int K, int Nout) {
  __shared__ float As[16][128];
  __shared__ float Bs[16][64];
  int tid = threadIdx.x;
  int tx = tid & 15;
  int ty = tid >> 4;
  int m0 = blockIdx.x * 128;
  int n0 = blockIdx.y * 64;
  float acc[8][4] = {};

  for (int k0 = 0; k0 < K; k0 += 16) {
#pragma unroll
    for (int i = 0; i < 2; i++) {
      int l4 = tid + i * 256;
      int row = l4 >> 2;
      int cg = (l4 & 3) * 4;
      int grow = m0 + row;
      float4 v = make_float4(0.f, 0.f, 0.f, 0.f);
      if (grow < M) v = *(const float4*)(A + (size_t)grow * K + k0 + cg);
      As[cg + 0][row] = v.x;
      As[cg + 1][row] = v.y;
      As[cg + 2][row] = v.z;
      As[cg + 3][row] = v.w;
    }
    {
      int r = tid >> 4;
      int cg = (tid & 15) * 4;
      float4 v = *(const float4*)(W + (size_t)(k0 + r) * Nout + n0 + cg);
      *(float4*)&Bs[r][cg] = v;
    }
    __syncthreads();
#pragma unroll
    for (int k = 0; k < 16; k++) {
      float4 b = *(float4*)&Bs[k][tx * 4];
      float4 a0 = *(const float4*)&As[k][ty * 8];
      float4 a1 = *(const float4*)&As[k][ty * 8 + 4];
      float a[8] = {a0.x, a0.y, a0.z, a0.w, a1.x, a1.y, a1.z, a1.w};
#pragma unroll
      for (int i = 0; i < 8; i++) {
        acc[i][0] = fmaf(a[i], b.x, acc[i][0]);
        acc[i][1] = fmaf(a[i], b.y, acc[i][1]);
        acc[i][2] = fmaf(a[i], b.z, acc[i][2]);
        acc[i][3] = fmaf(a[i], b.w, acc[i][3]);
      }
    }
    __syncthreads();
  }

  float4 bv = *(const float4*)(bias + n0 + tx * 4);
#pragma unroll
  for (int i = 0; i < 8; i++) {
    int grow = m0 + ty * 8 + i;
    if (grow < M) {
      float4 o;
      o.x = acc[i][0] + bv.x;
      o.y = acc[i][1] + bv.y;
      o.z = acc[i][2] + bv.z;
      o.w = acc[i][3] + bv.w;
      *(float4*)(C + (size_t)grow * Nout + n0 + tx * 4) = o;
    }
  }
}

// ---- GEMM for propagate-first layers (L3, L4): C = A@W + rowsum[m]*bias[n], relu, BN stats ----
__global__ __launch_bounds__(256) void gemm_rs_relu_stats(
    const float* __restrict__ A, const float* __restrict__ W,
    const float* __restrict__ bias, const float* __restrict__ rowsum,
    float* __restrict__ C, float* __restrict__ stat, int M, int K, int Nout) {
  __shared__ float As[16][128];
  __shared__ float Bs[16][64];
  __shared__ float red[16][64];
  int tid = threadIdx.x;
  int tx = tid & 15;
  int ty = tid >> 4;
  int m0 = blockIdx.x * 128;
  int n0 = blockIdx.y * 64;
  float acc[8][4] = {};

  for (int k0 = 0; k0 < K; k0 += 16) {
#pragma unroll
    for (int i = 0; i < 2; i++) {
      int l4 = tid + i * 256;
      int row = l4 >> 2;
      int cg = (l4 & 3) * 4;
      int grow = m0 + row;
      float4 v = make_float4(0.f, 0.f, 0.f, 0.f);
      if (grow < M) v = *(const float4*)(A + (size_t)grow * K + k0 + cg);
      As[cg + 0][row] = v.x;
      As[cg + 1][row] = v.y;
      As[cg + 2][row] = v.z;
      As[cg + 3][row] = v.w;
    }
    {
      int r = tid >> 4;
      int cg = (tid & 15) * 4;
      float4 v = *(const float4*)(W + (size_t)(k0 + r) * Nout + n0 + cg);
      *(float4*)&Bs[r][cg] = v;
    }
    __syncthreads();
#pragma unroll
    for (int k = 0; k < 16; k++) {
      float4 b = *(float4*)&Bs[k][tx * 4];
      float4 a0 = *(const float4*)&As[k][ty * 8];
      float4 a1 = *(const float4*)&As[k][ty * 8 + 4];
      float a[8] = {a0.x, a0.y, a0.z, a0.w, a1.x, a1.y, a1.z, a1.w};
#pragma unroll
      for (int i = 0; i < 8; i++) {
        acc[i][0] = fmaf(a[i], b.x, acc[i][0]);
        acc[i][1] = fmaf(a[i], b.y, acc[i][1]);
        acc[i][2] = fmaf(a[i], b.z, acc[i][2]);
        acc[i][3] = fmaf(a[i], b.w, acc[i][3]);
      }
    }
    __syncthreads();
  }

  float4 bv = *(const float4*)(bias + n0 + tx * 4);
  float lsum[4] = {0.f, 0.f, 0.f, 0.f};
  float lsq[4] = {0.f, 0.f, 0.f, 0.f};
#pragma unroll
  for (int i = 0; i < 8; i++) {
    int grow = m0 + ty * 8 + i;
    if (grow < M) {
      float rs = rowsum[grow];
      float4 o;
      o.x = fmaxf(fmaf(bv.x, rs, acc[i][0]), 0.f);
      o.y = fmaxf(fmaf(bv.y, rs, acc[i][1]), 0.f);
      o.z = fmaxf(fmaf(bv.z, rs, acc[i][2]), 0.f);
      o.w = fmaxf(fmaf(bv.w, rs, acc[i][3]), 0.f);
      *(float4*)(C + (size_t)grow * Nout + n0 + tx * 4) = o;
      lsum[0] += o.x; lsum[1] += o.y; lsum[2] += o.z; lsum[3] += o.w;
      lsq[0] = fmaf(o.x, o.x, lsq[0]);
      lsq[1] = fmaf(o.y, o.y, lsq[1]);
      lsq[2] = fmaf(o.z, o.z, lsq[2]);
      lsq[3] = fmaf(o.w, o.w, lsq[3]);
    }
  }
  __syncthreads();
#pragma unroll
  for (int j = 0; j < 4; j++) red[ty][tx * 4 + j] = lsum[j];
  __syncthreads();
  if (tid < 64) {
    float s = 0.f;
#pragma unroll
    for (int r = 0; r < 16; r++) s += red[r][tid];
    atomicAdd(&stat[n0 + tid], s);
  }
  __syncthreads();
#pragma unroll
  for (int j = 0; j < 4; j++) red[ty][tx * 4 + j] = lsq[j];
  __syncthreads();
  if (tid < 64) {
    float s = 0.f;
#pragma unroll
    for (int r = 0; r < 16; r++) s += red[r][tid];
    atomicAdd(&stat[256 + n0 + tid], s);
  }
}

// ---------------- aggregation (float4 lanes) ----------------
// RELU_STATS=true: fused relu + BN-stat accumulation (propagate-after layers)
// RELU_STATS=false: plain symmetric-normalized propagation (propagate-first layers)
template <int F, bool RELU_STATS>
__global__ __launch_bounds__(256) void agg_kernel(
    const float* __restrict__ hlin, const int* __restrict__ offs,
    const int* __restrict__ csr_src, const float* __restrict__ csr_w,
    const float* __restrict__ dinv, float* __restrict__ out,
    float* __restrict__ stat) {
  constexpr int TPN = F / 4;        // threads per node (one float4 each)
  constexpr int NPB = 256 / TPN;    // nodes per block-iteration
  int tid = threadIdx.x;
  int c4 = tid % TPN;
  int sub = tid / TPN;
  float4 lsum = make_float4(0.f, 0.f, 0.f, 0.f);
  float4 lsq = make_float4(0.f, 0.f, 0.f, 0.f);
  for (int node = blockIdx.x * NPB + sub; node < N_NODES; node += gridDim.x * NPB) {
    int e0 = offs[node], e1 = offs[node + 1];
    float4 acc = make_float4(0.f, 0.f, 0.f, 0.f);
    for (int e = e0; e < e1; e++) {
      int s = csr_src[e];
      float w = csr_w[e];
      float4 v = *(const float4*)(hlin + (size_t)s * F + c4 * 4);
      acc.x = fmaf(v.x, w, acc.x);
      acc.y = fmaf(v.y, w, acc.y);
      acc.z = fmaf(v.z, w, acc.z);
      acc.w = fmaf(v.w, w, acc.w);
    }
    float di = dinv[node];
    float ds = di * di;
    float4 v = *(const float4*)(hlin + (size_t)node * F + c4 * 4);
    acc.x = fmaf(v.x, ds, acc.x);
    acc.y = fmaf(v.y, ds, acc.y);
    acc.z = fmaf(v.z, ds, acc.z);
    acc.w = fmaf(v.w, ds, acc.w);
    if (RELU_STATS) {
      acc.x = fmaxf(acc.x, 0.f);
      acc.y = fmaxf(acc.y, 0.f);
      acc.z = fmaxf(acc.z, 0.f);
      acc.w = fmaxf(acc.w, 0.f);
      lsum.x += acc.x; lsum.y += acc.y; lsum.z += acc.z; lsum.w += acc.w;
      lsq.x = fmaf(acc.x, acc.x, lsq.x);
      lsq.y = fmaf(acc.y, acc.y, lsq.y);
      lsq.z = fmaf(acc.z, acc.z, lsq.z);
      lsq.w = fmaf(acc.w, acc.w, lsq.w);
    }
    *(float4*)(out + (size_t)node * F + c4 * 4) = acc;
  }
  if (RELU_STATS) {
    __shared__ float4 red[256];
    red[tid] = lsum;
    __syncthreads();
    if (tid < TPN) {
      float4 s = red[tid];
      for (int j = tid + TPN; j < 256; j += TPN) {
        float4 t = red[j];
        s.x += t.x; s.y += t.y; s.z += t.z; s.w += t.w;
      }
      atomicAdd(&stat[tid * 4 + 0], s.x);
      atomicAdd(&stat[tid * 4 + 1], s.y);
      atomicAdd(&stat[tid * 4 + 2], s.z);
      atomicAdd(&stat[tid * 4 + 3], s.w);
    }
    __syncthreads();
    red[tid] = lsq;
    __syncthreads();
    if (tid < TPN) {
      float4 s = red[tid];
      for (int j = tid + TPN; j < 256; j += TPN) {
        float4 t = red[j];
        s.x += t.x; s.y += t.y; s.z += t.z; s.w += t.w;
      }
      atomicAdd(&stat[256 + tid * 4 + 0], s.x);
      atomicAdd(&stat[256 + tid * 4 + 1], s.y);
      atomicAdd(&stat[256 + tid * 4 + 2], s.z);
      atomicAdd(&stat[256 + tid * 4 + 3], s.w);
    }
  }
}

// ---------------- BN finalize ----------------
__global__ void bn_finalize(const float* __restrict__ stat, const float* __restrict__ g,
                            const float* __restrict__ bb, float* __restrict__ scale,
                            float* __restrict__ shift, int F) {
  int c = threadIdx.x;
  if (c < F) {
    const float invN = 1.0f / (float)N_NODES;
    float mean = stat[c] * invN;
    float var = stat[256 + c] * invN - mean * mean;
    var = fmaxf(var, 0.f);
    float inv = rsqrtf(var + BN_EPS);
    float sc = g[c] * inv;
    scale[c] = sc;
    shift[c] = bb[c] - mean * sc;
  }
}

// ---------------- BN apply ----------------
template <int F, bool RELU>
__global__ __launch_bounds__(256) void bn_apply(const float* __restrict__ a,
                                                const float* __restrict__ scale,
                                                const float* __restrict__ shift,
                                                float* __restrict__ out) {
  constexpr int C4 = F / 4;
  const int total = N_NODES * C4;
  for (int idx = blockIdx.x * blockDim.x + threadIdx.x; idx < total;
       idx += gridDim.x * blockDim.x) {
    int c4 = idx % C4;
    float4 v = ((const float4*)a)[idx];
    float4 s = ((const float4*)scale)[c4];
    float4 sh = ((const float4*)shift)[c4];
    float4 o;
    o.x = fmaf(v.x, s.x, sh.x);
    o.y = fmaf(v.y, s.y, sh.y);
    o.z = fmaf(v.z, s.z, sh.z);
    o.w = fmaf(v.w, s.w, sh.w);
    if (RELU) {
      o.x = fmaxf(o.x, 0.f);
      o.y = fmaxf(o.y, 0.f);
      o.z = fmaxf(o.z, 0.f);
      o.w = fmaxf(o.w, 0.f);
    }
    ((float4*)out)[idx] = o;
  }
}

extern "C" void kernel_launch(void* const* d_in, const int* in_sizes, int n_in,
                              void* d_out, int out_size, void* d_ws, size_t ws_size,
                              hipStream_t stream) {
  const float* x = (const float*)d_in[0];
  const int* ei = (const int*)d_in[1];
  const int E = in_sizes[1] / 2;
  const int* src = ei;
  const int* dst = ei + E;
  const float* We1 = (const float*)d_in[2];  const float* be1 = (const float*)d_in[3];
  const float* g1  = (const float*)d_in[4];  const float* bb1 = (const float*)d_in[5];
  const float* We2 = (const float*)d_in[6];  const float* be2 = (const float*)d_in[7];
  const float* g2  = (const float*)d_in[8];  const float* bb2 = (const float*)d_in[9];
  const float* Wd1 = (const float*)d_in[10]; const float* bd1 = (const float*)d_in[11];
  const float* g3  = (const float*)d_in[12]; const float* bb3 = (const float*)d_in[13];
  const float* Wd2 = (const float*)d_in[14]; const float* bd2 = (const float*)d_in[15];
  const float* g4  = (const float*)d_in[16]; const float* bb4 = (const float*)d_in[17];

  float* out = (float*)d_out;
  char* ws = (char*)d_ws;
  float* bufA   = (float*)(ws + 0);            // 51,200,000
  float* bufB   = (float*)(ws + 51200000);     // 51,200,000
  int*   csrS   = (int*)(ws + 102400000);      // 3,200,000
  float* csrW   = (float*)(ws + 105600000);    // 3,200,000
  int*   counts = (int*)(ws + 108800000);      // 200,000
  int*   cursor = (int*)(ws + 109000000);      // 200,000 (freed after fill_csr)
  int*   offs   = (int*)(ws + 109200000);      // 200,004
  float* dinv   = (float*)(ws + 109400064);    // 200,000
  float* stat   = (float*)(ws + 109600064);    // 2,048
  float* scale  = (float*)(ws + 109602112);    // 1,024
  float* shift  = (float*)(ws + 109603136);    // 1,024
  if (ws_size < 109604160) return;
  float* rowsum = (float*)cursor;  // reuse cursor region after fill_csr

  float* enc1 = out + (size_t)N_NODES * F0;
  float* enc2 = enc1 + (size_t)N_NODES * F1;

  const int EB = (E + 255) / 256;
  const int AGG_GRID = 2048;

  // CSR build + normalization constants
  hipMemsetAsync(counts, 0, 2 * N_NODES * sizeof(int), stream);
  count_dst<<<EB, 256, 0, stream>>>(dst, counts, E);
  compute_dinv<<<(N_NODES + 255) / 256, 256, 0, stream>>>(counts, dinv);
  scan_offsets<<<1, 1024, 0, stream>>>(counts, offs);
  fill_csr<<<EB, 256, 0, stream>>>(src, dst, offs, cursor, dinv, csrS, csrW, E);
  compute_rowsum<<<(N_NODES + 255) / 256, 256, 0, stream>>>(offs, csrW, dinv, rowsum);

  const int MB = (N_NODES + 127) / 128;  // 391

  // ---- Layer 1: F0 -> F1 (propagate after: gather at 128) ----
  gemm_bias<<<dim3(MB, F1 / 64), 256, 0, stream>>>(x, We1, be1, bufA, N_NODES, F0, F1);
  hipMemsetAsync(stat, 0, 512 * sizeof(float), stream);
  agg_kernel<F1, true><<<AGG_GRID, 256, 0, stream>>>(bufA, offs, csrS, csrW, dinv, bufB, stat);
  bn_finalize<<<1, 256, 0, stream>>>(stat, g1, bb1, scale, shift, F1);
  bn_apply<F1, true><<<4096, 256, 0, stream>>>(bufB, scale, shift, enc1);

  // ---- Layer 2: F1 -> F2 (propagate after: gather at 64) ----
  gemm_bias<<<dim3(MB, F2 / 64), 256, 0, stream>>>(enc1, We2, be2, bufA, N_NODES, F1, F2);
  hipMemsetAsync(stat, 0, 512 * sizeof(float), stream);
  agg_kernel<F2, true><<<AGG_GRID, 256, 0, stream>>>(bufA, offs, csrS, csrW, dinv, bufB, stat);
  bn_finalize<<<1, 256, 0, stream>>>(stat, g2, bb2, scale, shift, F2);
  bn_apply<F2, false><<<4096, 256, 0, stream>>>(bufB, scale, shift, enc2);

  // ---- Layer 3: F2 -> F1 (propagate FIRST: gather at 64) ----
  agg_kernel<F2, false><<<AGG_GRID, 256, 0, stream>>>(enc2, offs, csrS, csrW, dinv, bufA, stat);
  hipMemsetAsync(stat, 0, 512 * sizeof(float), stream);
  gemm_rs_relu_stats<<<dim3(MB, F1 / 64), 256, 0, stream>>>(bufA, Wd1, bd1, rowsum, bufB,
                                                            stat, N_NODES, F2, F1);
  bn_finalize<<<1, 256, 0, stream>>>(stat, g3, bb3, scale, shift, F1);
  bn_apply<F1, true><<<4096, 256, 0, stream>>>(bufB, scale, shift, bufB);

  // ---- Layer 4: F1 -> F0 (propagate FIRST: gather at 128) ----
  agg_kernel<F1, false><<<AGG_GRID, 256, 0, stream>>>(bufB, offs, csrS, csrW, dinv, bufA, stat);
  hipMemsetAsync(stat, 0, 512 * sizeof(float), stream);
  gemm_rs_relu_stats<<<dim3(MB, F0 / 64), 256, 0, stream>>>(bufA, Wd2, bd2, rowsum, bufB,
                                                            stat, N_NODES, F1, F0);
  bn_finalize<<<1, 256, 0, stream>>>(stat, g4, bb4, scale, shift, F0);
  bn_apply<F0, false><<<4096, 256, 0, stream>>>(bufB, scale, shift, out);
}

// Round 3
// 739.061 us; speedup vs baseline: 1.4473x; 1.3859x over previous
//
#include <hip/hip_runtime.h>

#define N_NODES 50000
#define F0 256
#define F1 128
#define F2 64
#define BN_EPS 1e-5f

// ---------------- CSR build ----------------
__global__ void count_dst(const int* __restrict__ dst, int* __restrict__ counts, int E) {
  int e = blockIdx.x * blockDim.x + threadIdx.x;
  if (e < E) atomicAdd(&counts[dst[e]], 1);
}

__global__ void compute_dinv(const int* __restrict__ counts, float* __restrict__ dinv) {
  int i = blockIdx.x * blockDim.x + threadIdx.x;
  if (i < N_NODES) dinv[i] = rsqrtf((float)counts[i] + 1.0f);
}

__global__ __launch_bounds__(1024) void scan_offsets(const int* __restrict__ counts,
                                                     int* __restrict__ offs) {
  __shared__ int s_wsum[16];
  __shared__ int s_carry, s_total;
  int tid = threadIdx.x;
  int lane = tid & 63, wid = tid >> 6;
  if (tid == 0) s_carry = 0;
  __syncthreads();
  for (int base = 0; base < N_NODES; base += 1024) {
    int i = base + tid;
    int v = (i < N_NODES) ? counts[i] : 0;
    int incl = v;
#pragma unroll
    for (int d = 1; d < 64; d <<= 1) {
      int t = __shfl_up(incl, d);
      if (lane >= d) incl += t;
    }
    if (lane == 63) s_wsum[wid] = incl;
    __syncthreads();
    if (tid == 0) {
      int run = 0;
      for (int j = 0; j < 16; j++) { int t = s_wsum[j]; s_wsum[j] = run; run += t; }
      s_total = run;
    }
    __syncthreads();
    if (i < N_NODES) offs[i] = s_carry + s_wsum[wid] + incl - v;
    __syncthreads();
    if (tid == 0) s_carry += s_total;
    __syncthreads();
  }
  if (tid == 0) offs[N_NODES] = s_carry;
}

__global__ void fill_csr(const int* __restrict__ src, const int* __restrict__ dst,
                         const int* __restrict__ offs, int* __restrict__ cursor,
                         const float* __restrict__ dinv,
                         int* __restrict__ csr_src, float* __restrict__ csr_w, int E) {
  int e = blockIdx.x * blockDim.x + threadIdx.x;
  if (e < E) {
    int s = src[e], d = dst[e];
    int p = offs[d] + atomicAdd(&cursor[d], 1);
    csr_src[p] = s;
    csr_w[p] = dinv[s] * dinv[d];
  }
}

__global__ void compute_rowsum(const int* __restrict__ offs, const float* __restrict__ csr_w,
                               const float* __restrict__ dinv, float* __restrict__ rowsum) {
  int i = blockIdx.x * blockDim.x + threadIdx.x;
  if (i < N_NODES) {
    float s = dinv[i] * dinv[i];
    int e1 = offs[i + 1];
    for (int e = offs[i]; e < e1; e++) s += csr_w[e];
    rowsum[i] = s;
  }
}

// ---------------- fp32 tiled GEMM: C = A @ W + bias (L1, L2) ----------------
__global__ __launch_bounds__(256) void gemm_bias(const float* __restrict__ A,
                                                 const float* __restrict__ W,
                                                 const float* __restrict__ bias,
                                                 float* __restrict__ C,
                                                 int M, int K, int Nout) {
  __shared__ float As[16][128];
  __shared__ float Bs[16][64];
  int tid = threadIdx.x;
  int tx = tid & 15;
  int ty = tid >> 4;
  int m0 = blockIdx.x * 128;
  int n0 = blockIdx.y * 64;
  float acc[8][4] = {};

  for (int k0 = 0; k0 < K; k0 += 16) {
#pragma unroll
    for (int i = 0; i < 2; i++) {
      int l4 = tid + i * 256;
      int row = l4 >> 2;
      int cg = (l4 & 3) * 4;
      int grow = m0 + row;
      float4 v = make_float4(0.f, 0.f, 0.f, 0.f);
      if (grow < M) v = *(const float4*)(A + (size_t)grow * K + k0 + cg);
      As[cg + 0][row] = v.x;
      As[cg + 1][row] = v.y;
      As[cg + 2][row] = v.z;
      As[cg + 3][row] = v.w;
    }
    {
      int r = tid >> 4;
      int cg = (tid & 15) * 4;
      float4 v = *(const float4*)(W + (size_t)(k0 + r) * Nout + n0 + cg);
      *(float4*)&Bs[r][cg] = v;
    }
    __syncthreads();
#pragma unroll
    for (int k = 0; k < 16; k++) {
      float4 b = *(float4*)&Bs[k][tx * 4];
      float4 a0 = *(const float4*)&As[k][ty * 8];
      float4 a1 = *(const float4*)&As[k][ty * 8 + 4];
      float a[8] = {a0.x, a0.y, a0.z, a0.w, a1.x, a1.y, a1.z, a1.w};
#pragma unroll
      for (int i = 0; i < 8; i++) {
        acc[i][0] = fmaf(a[i], b.x, acc[i][0]);
        acc[i][1] = fmaf(a[i], b.y, acc[i][1]);
        acc[i][2] = fmaf(a[i], b.z, acc[i][2]);
        acc[i][3] = fmaf(a[i], b.w, acc[i][3]);
      }
    }
    __syncthreads();
  }

  float4 bv = *(const float4*)(bias + n0 + tx * 4);
#pragma unroll
  for (int i = 0; i < 8; i++) {
    int grow = m0 + ty * 8 + i;
    if (grow < M) {
      float4 o;
      o.x = acc[i][0] + bv.x;
      o.y = acc[i][1] + bv.y;
      o.z = acc[i][2] + bv.z;
      o.w = acc[i][3] + bv.w;
      *(float4*)(C + (size_t)grow * Nout + n0 + tx * 4) = o;
    }
  }
}

// ---- GEMM for propagate-first layers (L3, L4): C = A@W + rowsum[m]*bias[n], relu, BN stats ----
__global__ __launch_bounds__(256) void gemm_rs_relu_stats(
    const float* __restrict__ A, const float* __restrict__ W,
    const float* __restrict__ bias, const float* __restrict__ rowsum,
    float* __restrict__ C, float* __restrict__ stat, int M, int K, int Nout) {
  __shared__ float As[16][128];
  __shared__ float Bs[16][64];
  __shared__ float red[16][64];
  int tid = threadIdx.x;
  int tx = tid & 15;
  int ty = tid >> 4;
  int m0 = blockIdx.x * 128;
  int n0 = blockIdx.y * 64;
  float acc[8][4] = {};

  for (int k0 = 0; k0 < K; k0 += 16) {
#pragma unroll
    for (int i = 0; i < 2; i++) {
      int l4 = tid + i * 256;
      int row = l4 >> 2;
      int cg = (l4 & 3) * 4;
      int grow = m0 + row;
      float4 v = make_float4(0.f, 0.f, 0.f, 0.f);
      if (grow < M) v = *(const float4*)(A + (size_t)grow * K + k0 + cg);
      As[cg + 0][row] = v.x;
      As[cg + 1][row] = v.y;
      As[cg + 2][row] = v.z;
      As[cg + 3][row] = v.w;
    }
    {
      int r = tid >> 4;
      int cg = (tid & 15) * 4;
      float4 v = *(const float4*)(W + (size_t)(k0 + r) * Nout + n0 + cg);
      *(float4*)&Bs[r][cg] = v;
    }
    __syncthreads();
#pragma unroll
    for (int k = 0; k < 16; k++) {
      float4 b = *(float4*)&Bs[k][tx * 4];
      float4 a0 = *(const float4*)&As[k][ty * 8];
      float4 a1 = *(const float4*)&As[k][ty * 8 + 4];
      float a[8] = {a0.x, a0.y, a0.z, a0.w, a1.x, a1.y, a1.z, a1.w};
#pragma unroll
      for (int i = 0; i < 8; i++) {
        acc[i][0] = fmaf(a[i], b.x, acc[i][0]);
        acc[i][1] = fmaf(a[i], b.y, acc[i][1]);
        acc[i][2] = fmaf(a[i], b.z, acc[i][2]);
        acc[i][3] = fmaf(a[i], b.w, acc[i][3]);
      }
    }
    __syncthreads();
  }

  float4 bv = *(const float4*)(bias + n0 + tx * 4);
  float lsum[4] = {0.f, 0.f, 0.f, 0.f};
  float lsq[4] = {0.f, 0.f, 0.f, 0.f};
#pragma unroll
  for (int i = 0; i < 8; i++) {
    int grow = m0 + ty * 8 + i;
    if (grow < M) {
      float rs = rowsum[grow];
      float4 o;
      o.x = fmaxf(fmaf(bv.x, rs, acc[i][0]), 0.f);
      o.y = fmaxf(fmaf(bv.y, rs, acc[i][1]), 0.f);
      o.z = fmaxf(fmaf(bv.z, rs, acc[i][2]), 0.f);
      o.w = fmaxf(fmaf(bv.w, rs, acc[i][3]), 0.f);
      *(float4*)(C + (size_t)grow * Nout + n0 + tx * 4) = o;
      lsum[0] += o.x; lsum[1] += o.y; lsum[2] += o.z; lsum[3] += o.w;
      lsq[0] = fmaf(o.x, o.x, lsq[0]);
      lsq[1] = fmaf(o.y, o.y, lsq[1]);
      lsq[2] = fmaf(o.z, o.z, lsq[2]);
      lsq[3] = fmaf(o.w, o.w, lsq[3]);
    }
  }
  __syncthreads();
#pragma unroll
  for (int j = 0; j < 4; j++) red[ty][tx * 4 + j] = lsum[j];
  __syncthreads();
  if (tid < 64) {
    float s = 0.f;
#pragma unroll
    for (int r = 0; r < 16; r++) s += red[r][tid];
    atomicAdd(&stat[n0 + tid], s);
  }
  __syncthreads();
#pragma unroll
  for (int j = 0; j < 4; j++) red[ty][tx * 4 + j] = lsq[j];
  __syncthreads();
  if (tid < 64) {
    float s = 0.f;
#pragma unroll
    for (int r = 0; r < 16; r++) s += red[r][tid];
    atomicAdd(&stat[256 + n0 + tid], s);
  }
}

// ---------------- aggregation: ONE NODE PER WAVE ----------------
// Lanes cover channels (C = F/64 floats each) -> every gather is a coalesced
// full-row read. Edge indices/weights loaded 64-at-a-time (coalesced),
// broadcast via shuffle; gather loop unrolled x8 for 8 outstanding loads.
template <int F, bool RELU_STATS>
__global__ __launch_bounds__(256) void agg_wave(
    const float* __restrict__ hlin, const int* __restrict__ offs,
    const int* __restrict__ csr_src, const float* __restrict__ csr_w,
    const float* __restrict__ dinv, float* __restrict__ out,
    float* __restrict__ stat) {
  constexpr int C = F / 64;  // floats per lane
  typedef float vec_t __attribute__((ext_vector_type(C)));
  const int tid = threadIdx.x;
  const int lane = tid & 63;
  const int widx = tid >> 6;
  const int nwaves = gridDim.x * 4;

  float lsum[C], lsq[C];
#pragma unroll
  for (int c = 0; c < C; c++) { lsum[c] = 0.f; lsq[c] = 0.f; }

  for (int node = blockIdx.x * 4 + widx; node < N_NODES; node += nwaves) {
    const int e0 = offs[node], e1 = offs[node + 1];
    vec_t acc = (vec_t)(0.f);
    for (int e = e0; e < e1; e += 64) {
      const int cnt = min(64, e1 - e);
      int idx = 0;
      float wt = 0.f;
      if (lane < cnt) {
        idx = csr_src[e + lane];
        wt = csr_w[e + lane];
      }
      int j = 0;
      for (; j + 8 <= cnt; j += 8) {
        int s0 = __shfl(idx, j + 0); float w0 = __shfl(wt, j + 0);
        int s1 = __shfl(idx, j + 1); float w1 = __shfl(wt, j + 1);
        int s2 = __shfl(idx, j + 2); float w2 = __shfl(wt, j + 2);
        int s3 = __shfl(idx, j + 3); float w3 = __shfl(wt, j + 3);
        int s4 = __shfl(idx, j + 4); float w4 = __shfl(wt, j + 4);
        int s5 = __shfl(idx, j + 5); float w5 = __shfl(wt, j + 5);
        int s6 = __shfl(idx, j + 6); float w6 = __shfl(wt, j + 6);
        int s7 = __shfl(idx, j + 7); float w7 = __shfl(wt, j + 7);
        vec_t v0 = *(const vec_t*)(hlin + (size_t)s0 * F + lane * C);
        vec_t v1 = *(const vec_t*)(hlin + (size_t)s1 * F + lane * C);
        vec_t v2 = *(const vec_t*)(hlin + (size_t)s2 * F + lane * C);
        vec_t v3 = *(const vec_t*)(hlin + (size_t)s3 * F + lane * C);
        vec_t v4 = *(const vec_t*)(hlin + (size_t)s4 * F + lane * C);
        vec_t v5 = *(const vec_t*)(hlin + (size_t)s5 * F + lane * C);
        vec_t v6 = *(const vec_t*)(hlin + (size_t)s6 * F + lane * C);
        vec_t v7 = *(const vec_t*)(hlin + (size_t)s7 * F + lane * C);
        acc += w0 * v0 + w1 * v1 + w2 * v2 + w3 * v3;
        acc += w4 * v4 + w5 * v5 + w6 * v6 + w7 * v7;
      }
      for (; j < cnt; j++) {
        int s = __shfl(idx, j);
        float w = __shfl(wt, j);
        vec_t v = *(const vec_t*)(hlin + (size_t)s * F + lane * C);
        acc += w * v;
      }
    }
    float di = dinv[node];
    vec_t vs = *(const vec_t*)(hlin + (size_t)node * F + lane * C);
    acc += (di * di) * vs;
    if (RELU_STATS) {
#pragma unroll
      for (int c = 0; c < C; c++) {
        float a = fmaxf(acc[c], 0.f);
        acc[c] = a;
        lsum[c] += a;
        lsq[c] = fmaf(a, a, lsq[c]);
      }
    }
    *(vec_t*)(out + (size_t)node * F + lane * C) = acc;
  }

  if (RELU_STATS) {
    __shared__ float red[4][F];
#pragma unroll
    for (int c = 0; c < C; c++) red[widx][lane * C + c] = lsum[c];
    __syncthreads();
    if (tid < F) {
      float s = red[0][tid] + red[1][tid] + red[2][tid] + red[3][tid];
      atomicAdd(&stat[tid], s);
    }
    __syncthreads();
#pragma unroll
    for (int c = 0; c < C; c++) red[widx][lane * C + c] = lsq[c];
    __syncthreads();
    if (tid < F) {
      float s = red[0][tid] + red[1][tid] + red[2][tid] + red[3][tid];
      atomicAdd(&stat[256 + tid], s);
    }
  }
}

// ---------------- BN finalize ----------------
__global__ void bn_finalize(const float* __restrict__ stat, const float* __restrict__ g,
                            const float* __restrict__ bb, float* __restrict__ scale,
                            float* __restrict__ shift, int F) {
  int c = threadIdx.x;
  if (c < F) {
    const float invN = 1.0f / (float)N_NODES;
    float mean = stat[c] * invN;
    float var = stat[256 + c] * invN - mean * mean;
    var = fmaxf(var, 0.f);
    float inv = rsqrtf(var + BN_EPS);
    float sc = g[c] * inv;
    scale[c] = sc;
    shift[c] = bb[c] - mean * sc;
  }
}

// ---------------- BN apply ----------------
template <int F, bool RELU>
__global__ __launch_bounds__(256) void bn_apply(const float* __restrict__ a,
                                                const float* __restrict__ scale,
                                                const float* __restrict__ shift,
                                                float* __restrict__ out) {
  constexpr int C4 = F / 4;
  const int total = N_NODES * C4;
  for (int idx = blockIdx.x * blockDim.x + threadIdx.x; idx < total;
       idx += gridDim.x * blockDim.x) {
    int c4 = idx % C4;
    float4 v = ((const float4*)a)[idx];
    float4 s = ((const float4*)scale)[c4];
    float4 sh = ((const float4*)shift)[c4];
    float4 o;
    o.x = fmaf(v.x, s.x, sh.x);
    o.y = fmaf(v.y, s.y, sh.y);
    o.z = fmaf(v.z, s.z, sh.z);
    o.w = fmaf(v.w, s.w, sh.w);
    if (RELU) {
      o.x = fmaxf(o.x, 0.f);
      o.y = fmaxf(o.y, 0.f);
      o.z = fmaxf(o.z, 0.f);
      o.w = fmaxf(o.w, 0.f);
    }
    ((float4*)out)[idx] = o;
  }
}

extern "C" void kernel_launch(void* const* d_in, const int* in_sizes, int n_in,
                              void* d_out, int out_size, void* d_ws, size_t ws_size,
                              hipStream_t stream) {
  const float* x = (const float*)d_in[0];
  const int* ei = (const int*)d_in[1];
  const int E = in_sizes[1] / 2;
  const int* src = ei;
  const int* dst = ei + E;
  const float* We1 = (const float*)d_in[2];  const float* be1 = (const float*)d_in[3];
  const float* g1  = (const float*)d_in[4];  const float* bb1 = (const float*)d_in[5];
  const float* We2 = (const float*)d_in[6];  const float* be2 = (const float*)d_in[7];
  const float* g2  = (const float*)d_in[8];  const float* bb2 = (const float*)d_in[9];
  const float* Wd1 = (const float*)d_in[10]; const float* bd1 = (const float*)d_in[11];
  const float* g3  = (const float*)d_in[12]; const float* bb3 = (const float*)d_in[13];
  const float* Wd2 = (const float*)d_in[14]; const float* bd2 = (const float*)d_in[15];
  const float* g4  = (const float*)d_in[16]; const float* bb4 = (const float*)d_in[17];

  float* out = (float*)d_out;
  char* ws = (char*)d_ws;
  float* bufA   = (float*)(ws + 0);            // 51,200,000
  float* bufB   = (float*)(ws + 51200000);     // 51,200,000
  int*   csrS   = (int*)(ws + 102400000);      // 3,200,000
  float* csrW   = (float*)(ws + 105600000);    // 3,200,000
  int*   counts = (int*)(ws + 108800000);      // 200,000
  int*   cursor = (int*)(ws + 109000000);      // 200,000 (freed after fill_csr)
  int*   offs   = (int*)(ws + 109200000);      // 200,004
  float* dinv   = (float*)(ws + 109400064);    // 200,000
  float* stat   = (float*)(ws + 109600064);    // 2,048
  float* scale  = (float*)(ws + 109602112);    // 1,024
  float* shift  = (float*)(ws + 109603136);    // 1,024
  if (ws_size < 109604160) return;
  float* rowsum = (float*)cursor;  // reuse cursor region after fill_csr

  float* enc1 = out + (size_t)N_NODES * F0;
  float* enc2 = enc1 + (size_t)N_NODES * F1;

  const int EB = (E + 255) / 256;
  const int AGG_GRID = 2048;  // x4 waves = 8192 waves = full wave capacity

  // CSR build + normalization constants
  hipMemsetAsync(counts, 0, 2 * N_NODES * sizeof(int), stream);
  count_dst<<<EB, 256, 0, stream>>>(dst, counts, E);
  compute_dinv<<<(N_NODES + 255) / 256, 256, 0, stream>>>(counts, dinv);
  scan_offsets<<<1, 1024, 0, stream>>>(counts, offs);
  fill_csr<<<EB, 256, 0, stream>>>(src, dst, offs, cursor, dinv, csrS, csrW, E);
  compute_rowsum<<<(N_NODES + 255) / 256, 256, 0, stream>>>(offs, csrW, dinv, rowsum);

  const int MB = (N_NODES + 127) / 128;  // 391

  // ---- Layer 1: F0 -> F1 (propagate after: gather at 128) ----
  gemm_bias<<<dim3(MB, F1 / 64), 256, 0, stream>>>(x, We1, be1, bufA, N_NODES, F0, F1);
  hipMemsetAsync(stat, 0, 512 * sizeof(float), stream);
  agg_wave<F1, true><<<AGG_GRID, 256, 0, stream>>>(bufA, offs, csrS, csrW, dinv, bufB, stat);
  bn_finalize<<<1, 256, 0, stream>>>(stat, g1, bb1, scale, shift, F1);
  bn_apply<F1, true><<<4096, 256, 0, stream>>>(bufB, scale, shift, enc1);

  // ---- Layer 2: F1 -> F2 (propagate after: gather at 64) ----
  gemm_bias<<<dim3(MB, F2 / 64), 256, 0, stream>>>(enc1, We2, be2, bufA, N_NODES, F1, F2);
  hipMemsetAsync(stat, 0, 512 * sizeof(float), stream);
  agg_wave<F2, true><<<AGG_GRID, 256, 0, stream>>>(bufA, offs, csrS, csrW, dinv, bufB, stat);
  bn_finalize<<<1, 256, 0, stream>>>(stat, g2, bb2, scale, shift, F2);
  bn_apply<F2, false><<<4096, 256, 0, stream>>>(bufB, scale, shift, enc2);

  // ---- Layer 3: F2 -> F1 (propagate FIRST: gather at 64) ----
  agg_wave<F2, false><<<AGG_GRID, 256, 0, stream>>>(enc2, offs, csrS, csrW, dinv, bufA, stat);
  hipMemsetAsync(stat, 0, 512 * sizeof(float), stream);
  gemm_rs_relu_stats<<<dim3(MB, F1 / 64), 256, 0, stream>>>(bufA, Wd1, bd1, rowsum, bufB,
                                                            stat, N_NODES, F2, F1);
  bn_finalize<<<1, 256, 0, stream>>>(stat, g3, bb3, scale, shift, F1);
  bn_apply<F1, true><<<4096, 256, 0, stream>>>(bufB, scale, shift, bufB);

  // ---- Layer 4: F1 -> F0 (propagate FIRST: gather at 128) ----
  agg_wave<F1, false><<<AGG_GRID, 256, 0, stream>>>(bufB, offs, csrS, csrW, dinv, bufA, stat);
  hipMemsetAsync(stat, 0, 512 * sizeof(float), stream);
  gemm_rs_relu_stats<<<dim3(MB, F0 / 64), 256, 0, stream>>>(bufA, Wd2, bd2, rowsum, bufB,
                                                            stat, N_NODES, F1, F0);
  bn_finalize<<<1, 256, 0, stream>>>(stat, g4, bb4, scale, shift, F0);
  bn_apply<F0, false><<<4096, 256, 0, stream>>>(bufB, scale, shift, out);
}

// Round 4
// 687.151 us; speedup vs baseline: 1.5566x; 1.0755x over previous
//
#include <hip/hip_runtime.h>

#define N_NODES 50000
#define F0 256
#define F1 128
#define F2 64
#define BN_EPS 1e-5f

__device__ __forceinline__ float bflo(unsigned v) { return __uint_as_float(v << 16); }
__device__ __forceinline__ float bfhi(unsigned v) { return __uint_as_float(v & 0xFFFF0000u); }
__device__ __forceinline__ unsigned short f2bf(float f) {
  unsigned u = __float_as_uint(f);
  u += 0x7FFFu + ((u >> 16) & 1u);
  return (unsigned short)(u >> 16);
}

// ---------------- CSR build ----------------
__global__ void count_dst(const int* __restrict__ dst, int* __restrict__ counts, int E) {
  int e = blockIdx.x * blockDim.x + threadIdx.x;
  if (e < E) atomicAdd(&counts[dst[e]], 1);
}

__global__ void compute_dinv(const int* __restrict__ counts, float* __restrict__ dinv) {
  int i = blockIdx.x * blockDim.x + threadIdx.x;
  if (i < N_NODES) dinv[i] = rsqrtf((float)counts[i] + 1.0f);
}

__global__ __launch_bounds__(1024) void scan_offsets(const int* __restrict__ counts,
                                                     int* __restrict__ offs) {
  __shared__ int s_wsum[16];
  __shared__ int s_carry, s_total;
  int tid = threadIdx.x;
  int lane = tid & 63, wid = tid >> 6;
  if (tid == 0) s_carry = 0;
  __syncthreads();
  for (int base = 0; base < N_NODES; base += 1024) {
    int i = base + tid;
    int v = (i < N_NODES) ? counts[i] : 0;
    int incl = v;
#pragma unroll
    for (int d = 1; d < 64; d <<= 1) {
      int t = __shfl_up(incl, d);
      if (lane >= d) incl += t;
    }
    if (lane == 63) s_wsum[wid] = incl;
    __syncthreads();
    if (tid == 0) {
      int run = 0;
      for (int j = 0; j < 16; j++) { int t = s_wsum[j]; s_wsum[j] = run; run += t; }
      s_total = run;
    }
    __syncthreads();
    if (i < N_NODES) offs[i] = s_carry + s_wsum[wid] + incl - v;
    __syncthreads();
    if (tid == 0) s_carry += s_total;
    __syncthreads();
  }
  if (tid == 0) offs[N_NODES] = s_carry;
}

__global__ void fill_csr(const int* __restrict__ src, const int* __restrict__ dst,
                         const int* __restrict__ offs, int* __restrict__ cursor,
                         const float* __restrict__ dinv,
                         int* __restrict__ csr_src, float* __restrict__ csr_w, int E) {
  int e = blockIdx.x * blockDim.x + threadIdx.x;
  if (e < E) {
    int s = src[e], d = dst[e];
    int p = offs[d] + atomicAdd(&cursor[d], 1);
    csr_src[p] = s;
    csr_w[p] = dinv[s] * dinv[d];
  }
}

__global__ void compute_rowsum(const int* __restrict__ offs, const float* __restrict__ csr_w,
                               const float* __restrict__ dinv, float* __restrict__ rowsum) {
  int i = blockIdx.x * blockDim.x + threadIdx.x;
  if (i < N_NODES) {
    float s = dinv[i] * dinv[i];
    int e1 = offs[i + 1];
    for (int e = offs[i]; e < e1; e++) s += csr_w[e];
    rowsum[i] = s;
  }
}

// ---------------- fp32 GEMM with bf16 output: C = bf16(A @ W + bias) ----------------
__global__ __launch_bounds__(256) void gemm_bias_b16(const float* __restrict__ A,
                                                     const float* __restrict__ W,
                                                     const float* __restrict__ bias,
                                                     unsigned short* __restrict__ Cb,
                                                     int M, int K, int Nout) {
  __shared__ float As[16][128];
  __shared__ float Bs[16][64];
  int tid = threadIdx.x;
  int tx = tid & 15;
  int ty = tid >> 4;
  int m0 = blockIdx.x * 128;
  int n0 = blockIdx.y * 64;
  float acc[8][4] = {};

  for (int k0 = 0; k0 < K; k0 += 16) {
#pragma unroll
    for (int i = 0; i < 2; i++) {
      int l4 = tid + i * 256;
      int row = l4 >> 2;
      int cg = (l4 & 3) * 4;
      int grow = m0 + row;
      float4 v = make_float4(0.f, 0.f, 0.f, 0.f);
      if (grow < M) v = *(const float4*)(A + (size_t)grow * K + k0 + cg);
      As[cg + 0][row] = v.x;
      As[cg + 1][row] = v.y;
      As[cg + 2][row] = v.z;
      As[cg + 3][row] = v.w;
    }
    {
      int r = tid >> 4;
      int cg = (tid & 15) * 4;
      float4 v = *(const float4*)(W + (size_t)(k0 + r) * Nout + n0 + cg);
      *(float4*)&Bs[r][cg] = v;
    }
    __syncthreads();
#pragma unroll
    for (int k = 0; k < 16; k++) {
      float4 b = *(float4*)&Bs[k][tx * 4];
      float4 a0 = *(const float4*)&As[k][ty * 8];
      float4 a1 = *(const float4*)&As[k][ty * 8 + 4];
      float a[8] = {a0.x, a0.y, a0.z, a0.w, a1.x, a1.y, a1.z, a1.w};
#pragma unroll
      for (int i = 0; i < 8; i++) {
        acc[i][0] = fmaf(a[i], b.x, acc[i][0]);
        acc[i][1] = fmaf(a[i], b.y, acc[i][1]);
        acc[i][2] = fmaf(a[i], b.z, acc[i][2]);
        acc[i][3] = fmaf(a[i], b.w, acc[i][3]);
      }
    }
    __syncthreads();
  }

  float4 bv = *(const float4*)(bias + n0 + tx * 4);
#pragma unroll
  for (int i = 0; i < 8; i++) {
    int grow = m0 + ty * 8 + i;
    if (grow < M) {
      ushort4 o;
      o.x = f2bf(acc[i][0] + bv.x);
      o.y = f2bf(acc[i][1] + bv.y);
      o.z = f2bf(acc[i][2] + bv.z);
      o.w = f2bf(acc[i][3] + bv.w);
      *(ushort4*)(Cb + (size_t)grow * Nout + n0 + tx * 4) = o;
    }
  }
}

// ---- GEMM for propagate-first layers (L3, L4): C = A@W + rowsum[m]*bias[n], relu, BN stats ----
__global__ __launch_bounds__(256) void gemm_rs_relu_stats(
    const float* __restrict__ A, const float* __restrict__ W,
    const float* __restrict__ bias, const float* __restrict__ rowsum,
    float* __restrict__ C, float* __restrict__ stat, int M, int K, int Nout) {
  __shared__ float As[16][128];
  __shared__ float Bs[16][64];
  __shared__ float red[16][64];
  int tid = threadIdx.x;
  int tx = tid & 15;
  int ty = tid >> 4;
  int m0 = blockIdx.x * 128;
  int n0 = blockIdx.y * 64;
  float acc[8][4] = {};

  for (int k0 = 0; k0 < K; k0 += 16) {
#pragma unroll
    for (int i = 0; i < 2; i++) {
      int l4 = tid + i * 256;
      int row = l4 >> 2;
      int cg = (l4 & 3) * 4;
      int grow = m0 + row;
      float4 v = make_float4(0.f, 0.f, 0.f, 0.f);
      if (grow < M) v = *(const float4*)(A + (size_t)grow * K + k0 + cg);
      As[cg + 0][row] = v.x;
      As[cg + 1][row] = v.y;
      As[cg + 2][row] = v.z;
      As[cg + 3][row] = v.w;
    }
    {
      int r = tid >> 4;
      int cg = (tid & 15) * 4;
      float4 v = *(const float4*)(W + (size_t)(k0 + r) * Nout + n0 + cg);
      *(float4*)&Bs[r][cg] = v;
    }
    __syncthreads();
#pragma unroll
    for (int k = 0; k < 16; k++) {
      float4 b = *(float4*)&Bs[k][tx * 4];
      float4 a0 = *(const float4*)&As[k][ty * 8];
      float4 a1 = *(const float4*)&As[k][ty * 8 + 4];
      float a[8] = {a0.x, a0.y, a0.z, a0.w, a1.x, a1.y, a1.z, a1.w};
#pragma unroll
      for (int i = 0; i < 8; i++) {
        acc[i][0] = fmaf(a[i], b.x, acc[i][0]);
        acc[i][1] = fmaf(a[i], b.y, acc[i][1]);
        acc[i][2] = fmaf(a[i], b.z, acc[i][2]);
        acc[i][3] = fmaf(a[i], b.w, acc[i][3]);
      }
    }
    __syncthreads();
  }

  float4 bv = *(const float4*)(bias + n0 + tx * 4);
  float lsum[4] = {0.f, 0.f, 0.f, 0.f};
  float lsq[4] = {0.f, 0.f, 0.f, 0.f};
#pragma unroll
  for (int i = 0; i < 8; i++) {
    int grow = m0 + ty * 8 + i;
    if (grow < M) {
      float rs = rowsum[grow];
      float4 o;
      o.x = fmaxf(fmaf(bv.x, rs, acc[i][0]), 0.f);
      o.y = fmaxf(fmaf(bv.y, rs, acc[i][1]), 0.f);
      o.z = fmaxf(fmaf(bv.z, rs, acc[i][2]), 0.f);
      o.w = fmaxf(fmaf(bv.w, rs, acc[i][3]), 0.f);
      *(float4*)(C + (size_t)grow * Nout + n0 + tx * 4) = o;
      lsum[0] += o.x; lsum[1] += o.y; lsum[2] += o.z; lsum[3] += o.w;
      lsq[0] = fmaf(o.x, o.x, lsq[0]);
      lsq[1] = fmaf(o.y, o.y, lsq[1]);
      lsq[2] = fmaf(o.z, o.z, lsq[2]);
      lsq[3] = fmaf(o.w, o.w, lsq[3]);
    }
  }
  __syncthreads();
#pragma unroll
  for (int j = 0; j < 4; j++) red[ty][tx * 4 + j] = lsum[j];
  __syncthreads();
  if (tid < 64) {
    float s = 0.f;
#pragma unroll
    for (int r = 0; r < 16; r++) s += red[r][tid];
    atomicAdd(&stat[n0 + tid], s);
  }
  __syncthreads();
#pragma unroll
  for (int j = 0; j < 4; j++) red[ty][tx * 4 + j] = lsq[j];
  __syncthreads();
  if (tid < 64) {
    float s = 0.f;
#pragma unroll
    for (int r = 0; r < 16; r++) s += red[r][tid];
    atomicAdd(&stat[256 + n0 + tid], s);
  }
}

// ---------------- agg, bf16 input, F=128: one node per wave, lane = 1 uint (2 ch) ----------------
template <bool RELU_STATS>
__global__ __launch_bounds__(256) void agg_wave_bf16_128(
    const unsigned short* __restrict__ hb, const int* __restrict__ offs,
    const int* __restrict__ csr_src, const float* __restrict__ csr_w,
    const float* __restrict__ dinv, float* __restrict__ out,
    float* __restrict__ stat) {
  const int tid = threadIdx.x;
  const int lane = tid & 63;
  const int widx = tid >> 6;
  const int nwaves = gridDim.x * 4;
  float ls0 = 0.f, ls1 = 0.f, lq0 = 0.f, lq1 = 0.f;

  for (int node = blockIdx.x * 4 + widx; node < N_NODES; node += nwaves) {
    const int e0 = offs[node], e1 = offs[node + 1];
    float a0 = 0.f, a1 = 0.f;
    for (int e = e0; e < e1; e += 64) {
      const int cnt = min(64, e1 - e);
      int idx = 0;
      float wt = 0.f;
      if (lane < cnt) {
        idx = csr_src[e + lane];
        wt = csr_w[e + lane];
      }
      int j = 0;
      for (; j + 8 <= cnt; j += 8) {
        int s0 = __shfl(idx, j + 0); float w0 = __shfl(wt, j + 0);
        int s1 = __shfl(idx, j + 1); float w1 = __shfl(wt, j + 1);
        int s2 = __shfl(idx, j + 2); float w2 = __shfl(wt, j + 2);
        int s3 = __shfl(idx, j + 3); float w3 = __shfl(wt, j + 3);
        int s4 = __shfl(idx, j + 4); float w4 = __shfl(wt, j + 4);
        int s5 = __shfl(idx, j + 5); float w5 = __shfl(wt, j + 5);
        int s6 = __shfl(idx, j + 6); float w6 = __shfl(wt, j + 6);
        int s7 = __shfl(idx, j + 7); float w7 = __shfl(wt, j + 7);
        unsigned v0 = *(const unsigned*)(hb + (size_t)s0 * 128 + lane * 2);
        unsigned v1 = *(const unsigned*)(hb + (size_t)s1 * 128 + lane * 2);
        unsigned v2 = *(const unsigned*)(hb + (size_t)s2 * 128 + lane * 2);
        unsigned v3 = *(const unsigned*)(hb + (size_t)s3 * 128 + lane * 2);
        unsigned v4 = *(const unsigned*)(hb + (size_t)s4 * 128 + lane * 2);
        unsigned v5 = *(const unsigned*)(hb + (size_t)s5 * 128 + lane * 2);
        unsigned v6 = *(const unsigned*)(hb + (size_t)s6 * 128 + lane * 2);
        unsigned v7 = *(const unsigned*)(hb + (size_t)s7 * 128 + lane * 2);
        a0 = fmaf(bflo(v0), w0, a0); a1 = fmaf(bfhi(v0), w0, a1);
        a0 = fmaf(bflo(v1), w1, a0); a1 = fmaf(bfhi(v1), w1, a1);
        a0 = fmaf(bflo(v2), w2, a0); a1 = fmaf(bfhi(v2), w2, a1);
        a0 = fmaf(bflo(v3), w3, a0); a1 = fmaf(bfhi(v3), w3, a1);
        a0 = fmaf(bflo(v4), w4, a0); a1 = fmaf(bfhi(v4), w4, a1);
        a0 = fmaf(bflo(v5), w5, a0); a1 = fmaf(bfhi(v5), w5, a1);
        a0 = fmaf(bflo(v6), w6, a0); a1 = fmaf(bfhi(v6), w6, a1);
        a0 = fmaf(bflo(v7), w7, a0); a1 = fmaf(bfhi(v7), w7, a1);
      }
      for (; j < cnt; j++) {
        int s = __shfl(idx, j);
        float w = __shfl(wt, j);
        unsigned v = *(const unsigned*)(hb + (size_t)s * 128 + lane * 2);
        a0 = fmaf(bflo(v), w, a0);
        a1 = fmaf(bfhi(v), w, a1);
      }
    }
    float di = dinv[node];
    float ds = di * di;
    unsigned vs = *(const unsigned*)(hb + (size_t)node * 128 + lane * 2);
    a0 = fmaf(bflo(vs), ds, a0);
    a1 = fmaf(bfhi(vs), ds, a1);
    if (RELU_STATS) {
      a0 = fmaxf(a0, 0.f);
      a1 = fmaxf(a1, 0.f);
      ls0 += a0; ls1 += a1;
      lq0 = fmaf(a0, a0, lq0);
      lq1 = fmaf(a1, a1, lq1);
    }
    *(float2*)(out + (size_t)node * 128 + lane * 2) = make_float2(a0, a1);
  }

  if (RELU_STATS) {
    __shared__ float red[4][128];
    red[widx][lane * 2 + 0] = ls0;
    red[widx][lane * 2 + 1] = ls1;
    __syncthreads();
    if (tid < 128) {
      atomicAdd(&stat[tid], red[0][tid] + red[1][tid] + red[2][tid] + red[3][tid]);
    }
    __syncthreads();
    red[widx][lane * 2 + 0] = lq0;
    red[widx][lane * 2 + 1] = lq1;
    __syncthreads();
    if (tid < 128) {
      atomicAdd(&stat[256 + tid], red[0][tid] + red[1][tid] + red[2][tid] + red[3][tid]);
    }
  }
}

// ---------------- agg, bf16 input, F=64: one node per wave, TWO edges per gather ----------------
template <bool RELU_STATS>
__global__ __launch_bounds__(256) void agg_wave_bf16_64(
    const unsigned short* __restrict__ hb, const int* __restrict__ offs,
    const int* __restrict__ csr_src, const float* __restrict__ csr_w,
    const float* __restrict__ dinv, float* __restrict__ out,
    float* __restrict__ stat) {
  const int tid = threadIdx.x;
  const int lane = tid & 63;
  const int widx = tid >> 6;
  const int half = lane >> 5;   // which edge of the pair this lane gathers
  const int hl = lane & 31;     // uint index within row (2 channels)
  const int nwaves = gridDim.x * 4;
  float ls0 = 0.f, ls1 = 0.f, lq0 = 0.f, lq1 = 0.f;

  for (int node = blockIdx.x * 4 + widx; node < N_NODES; node += nwaves) {
    const int e0 = offs[node], e1 = offs[node + 1];
    float a0 = 0.f, a1 = 0.f;
    for (int e = e0; e < e1; e += 64) {
      const int cnt = min(64, e1 - e);
      int idx = 0;
      float wt = 0.f;
      if (lane < cnt) {
        idx = csr_src[e + lane];
        wt = csr_w[e + lane];
      }
      int j = 0;
      for (; j + 16 <= cnt; j += 16) {
        int s0 = __shfl(idx, j + 0 + half);  float w0 = __shfl(wt, j + 0 + half);
        int s1 = __shfl(idx, j + 2 + half);  float w1 = __shfl(wt, j + 2 + half);
        int s2 = __shfl(idx, j + 4 + half);  float w2 = __shfl(wt, j + 4 + half);
        int s3 = __shfl(idx, j + 6 + half);  float w3 = __shfl(wt, j + 6 + half);
        int s4 = __shfl(idx, j + 8 + half);  float w4 = __shfl(wt, j + 8 + half);
        int s5 = __shfl(idx, j + 10 + half); float w5 = __shfl(wt, j + 10 + half);
        int s6 = __shfl(idx, j + 12 + half); float w6 = __shfl(wt, j + 12 + half);
        int s7 = __shfl(idx, j + 14 + half); float w7 = __shfl(wt, j + 14 + half);
        unsigned v0 = *(const unsigned*)(hb + (size_t)s0 * 64 + hl * 2);
        unsigned v1 = *(const unsigned*)(hb + (size_t)s1 * 64 + hl * 2);
        unsigned v2 = *(const unsigned*)(hb + (size_t)s2 * 64 + hl * 2);
        unsigned v3 = *(const unsigned*)(hb + (size_t)s3 * 64 + hl * 2);
        unsigned v4 = *(const unsigned*)(hb + (size_t)s4 * 64 + hl * 2);
        unsigned v5 = *(const unsigned*)(hb + (size_t)s5 * 64 + hl * 2);
        unsigned v6 = *(const unsigned*)(hb + (size_t)s6 * 64 + hl * 2);
        unsigned v7 = *(const unsigned*)(hb + (size_t)s7 * 64 + hl * 2);
        a0 = fmaf(bflo(v0), w0, a0); a1 = fmaf(bfhi(v0), w0, a1);
        a0 = fmaf(bflo(v1), w1, a0); a1 = fmaf(bfhi(v1), w1, a1);
        a0 = fmaf(bflo(v2), w2, a0); a1 = fmaf(bfhi(v2), w2, a1);
        a0 = fmaf(bflo(v3), w3, a0); a1 = fmaf(bfhi(v3), w3, a1);
        a0 = fmaf(bflo(v4), w4, a0); a1 = fmaf(bfhi(v4), w4, a1);
        a0 = fmaf(bflo(v5), w5, a0); a1 = fmaf(bfhi(v5), w5, a1);
        a0 = fmaf(bflo(v6), w6, a0); a1 = fmaf(bfhi(v6), w6, a1);
        a0 = fmaf(bflo(v7), w7, a0); a1 = fmaf(bfhi(v7), w7, a1);
      }
      for (; j + 2 <= cnt; j += 2) {
        int s = __shfl(idx, j + half);
        float w = __shfl(wt, j + half);
        unsigned v = *(const unsigned*)(hb + (size_t)s * 64 + hl * 2);
        a0 = fmaf(bflo(v), w, a0);
        a1 = fmaf(bfhi(v), w, a1);
      }
      if (j < cnt) {  // odd leftover edge: half 0 only
        int s = __shfl(idx, j);
        float w = __shfl(wt, j);
        if (half == 0) {
          unsigned v = *(const unsigned*)(hb + (size_t)s * 64 + hl * 2);
          a0 = fmaf(bflo(v), w, a0);
          a1 = fmaf(bfhi(v), w, a1);
        }
      }
    }
    // combine the two edge-halves
    a0 += __shfl_xor(a0, 32);
    a1 += __shfl_xor(a1, 32);
    float di = dinv[node];
    float ds = di * di;
    unsigned vs = *(const unsigned*)(hb + (size_t)node * 64 + hl * 2);
    a0 = fmaf(bflo(vs), ds, a0);
    a1 = fmaf(bfhi(vs), ds, a1);
    if (RELU_STATS) {
      a0 = fmaxf(a0, 0.f);
      a1 = fmaxf(a1, 0.f);
      if (half == 0) {
        ls0 += a0; ls1 += a1;
        lq0 = fmaf(a0, a0, lq0);
        lq1 = fmaf(a1, a1, lq1);
      }
    }
    if (half == 0) {
      *(float2*)(out + (size_t)node * 64 + hl * 2) = make_float2(a0, a1);
    }
  }

  if (RELU_STATS) {
    __shared__ float red[4][64];
    if (half == 0) {
      red[widx][hl * 2 + 0] = ls0;
      red[widx][hl * 2 + 1] = ls1;
    }
    __syncthreads();
    if (tid < 64) {
      atomicAdd(&stat[tid], red[0][tid] + red[1][tid] + red[2][tid] + red[3][tid]);
    }
    __syncthreads();
    if (half == 0) {
      red[widx][hl * 2 + 0] = lq0;
      red[widx][hl * 2 + 1] = lq1;
    }
    __syncthreads();
    if (tid < 64) {
      atomicAdd(&stat[256 + tid], red[0][tid] + red[1][tid] + red[2][tid] + red[3][tid]);
    }
  }
}

// ---------------- BN finalize ----------------
__global__ void bn_finalize(const float* __restrict__ stat, const float* __restrict__ g,
                            const float* __restrict__ bb, float* __restrict__ scale,
                            float* __restrict__ shift, int F) {
  int c = threadIdx.x;
  if (c < F) {
    const float invN = 1.0f / (float)N_NODES;
    float mean = stat[c] * invN;
    float var = stat[256 + c] * invN - mean * mean;
    var = fmaxf(var, 0.f);
    float inv = rsqrtf(var + BN_EPS);
    float sc = g[c] * inv;
    scale[c] = sc;
    shift[c] = bb[c] - mean * sc;
  }
}

// ---------------- BN apply: optional fp32 and/or bf16 outputs ----------------
template <int F, bool RELU, bool WF32, bool WB16>
__global__ __launch_bounds__(256) void bn_apply2(const float* __restrict__ a,
                                                 const float* __restrict__ scale,
                                                 const float* __restrict__ shift,
                                                 float* __restrict__ outf,
                                                 unsigned short* __restrict__ outb) {
  constexpr int C4 = F / 4;
  const int total = N_NODES * C4;
  for (int idx = blockIdx.x * blockDim.x + threadIdx.x; idx < total;
       idx += gridDim.x * blockDim.x) {
    int c4 = idx % C4;
    float4 v = ((const float4*)a)[idx];
    float4 s = ((const float4*)scale)[c4];
    float4 sh = ((const float4*)shift)[c4];
    float4 o;
    o.x = fmaf(v.x, s.x, sh.x);
    o.y = fmaf(v.y, s.y, sh.y);
    o.z = fmaf(v.z, s.z, sh.z);
    o.w = fmaf(v.w, s.w, sh.w);
    if (RELU) {
      o.x = fmaxf(o.x, 0.f);
      o.y = fmaxf(o.y, 0.f);
      o.z = fmaxf(o.z, 0.f);
      o.w = fmaxf(o.w, 0.f);
    }
    if (WF32) ((float4*)outf)[idx] = o;
    if (WB16) {
      ushort4 b;
      b.x = f2bf(o.x);
      b.y = f2bf(o.y);
      b.z = f2bf(o.z);
      b.w = f2bf(o.w);
      ((ushort4*)outb)[idx] = b;
    }
  }
}

extern "C" void kernel_launch(void* const* d_in, const int* in_sizes, int n_in,
                              void* d_out, int out_size, void* d_ws, size_t ws_size,
                              hipStream_t stream) {
  const float* x = (const float*)d_in[0];
  const int* ei = (const int*)d_in[1];
  const int E = in_sizes[1] / 2;
  const int* src = ei;
  const int* dst = ei + E;
  const float* We1 = (const float*)d_in[2];  const float* be1 = (const float*)d_in[3];
  const float* g1  = (const float*)d_in[4];  const float* bb1 = (const float*)d_in[5];
  const float* We2 = (const float*)d_in[6];  const float* be2 = (const float*)d_in[7];
  const float* g2  = (const float*)d_in[8];  const float* bb2 = (const float*)d_in[9];
  const float* Wd1 = (const float*)d_in[10]; const float* bd1 = (const float*)d_in[11];
  const float* g3  = (const float*)d_in[12]; const float* bb3 = (const float*)d_in[13];
  const float* Wd2 = (const float*)d_in[14]; const float* bd2 = (const float*)d_in[15];
  const float* g4  = (const float*)d_in[16]; const float* bb4 = (const float*)d_in[17];

  float* out = (float*)d_out;
  char* ws = (char*)d_ws;
  // regionA = [0, 51.2MB): aliased bf16/fp32 intermediates (lifetimes disjoint)
  // regionB = [51.2MB, 102.4MB): pre-BN fp32 buffer
  unsigned short* A0b = (unsigned short*)(ws + 0);          // L1 gemm out bf16 50000x128
  unsigned short* A1b = (unsigned short*)(ws + 0);          // L2 gemm out bf16 50000x64
  unsigned short* C2b = (unsigned short*)(ws + 16000000);   // h2 bf16 copy 50000x64
  float*          A3f = (float*)(ws + 32000000);            // L3 agg out fp32 50000x64
  unsigned short* D3b = (unsigned short*)(ws + 0);          // h3 bf16 50000x128
  float*          A4f = (float*)(ws + 16000000);            // L4 agg out fp32 50000x128
  float*          B0f = (float*)(ws + 51200000);            // pre-BN fp32 (max 50000x256... only 128 used? no: L4 gemm out is 256ch = 51.2MB) fits exactly
  int*   csrS   = (int*)(ws + 102400000);
  float* csrW   = (float*)(ws + 105600000);
  int*   counts = (int*)(ws + 108800000);
  int*   cursor = (int*)(ws + 109000000);
  int*   offs   = (int*)(ws + 109200000);
  float* dinv   = (float*)(ws + 109400064);
  float* stat   = (float*)(ws + 109600064);
  float* scale  = (float*)(ws + 109602112);
  float* shift  = (float*)(ws + 109603136);
  if (ws_size < 109604160) return;
  float* rowsum = (float*)cursor;  // reuse cursor region after fill_csr

  float* enc1 = out + (size_t)N_NODES * F0;
  float* enc2 = enc1 + (size_t)N_NODES * F1;

  const int EB = (E + 255) / 256;
  const int AGG_GRID = 2048;
  const int MB = (N_NODES + 127) / 128;  // 391

  // CSR build + normalization constants
  hipMemsetAsync(counts, 0, 2 * N_NODES * sizeof(int), stream);
  count_dst<<<EB, 256, 0, stream>>>(dst, counts, E);
  compute_dinv<<<(N_NODES + 255) / 256, 256, 0, stream>>>(counts, dinv);
  scan_offsets<<<1, 1024, 0, stream>>>(counts, offs);
  fill_csr<<<EB, 256, 0, stream>>>(src, dst, offs, cursor, dinv, csrS, csrW, E);
  compute_rowsum<<<(N_NODES + 255) / 256, 256, 0, stream>>>(offs, csrW, dinv, rowsum);

  // ---- Layer 1: F0 -> F1 (propagate after, bf16 gather at 128) ----
  gemm_bias_b16<<<dim3(MB, 2), 256, 0, stream>>>(x, We1, be1, A0b, N_NODES, F0, F1);
  hipMemsetAsync(stat, 0, 512 * sizeof(float), stream);
  agg_wave_bf16_128<true><<<AGG_GRID, 256, 0, stream>>>(A0b, offs, csrS, csrW, dinv, B0f, stat);
  bn_finalize<<<1, 256, 0, stream>>>(stat, g1, bb1, scale, shift, F1);
  bn_apply2<F1, true, true, false><<<4096, 256, 0, stream>>>(B0f, scale, shift, enc1, nullptr);

  // ---- Layer 2: F1 -> F2 (propagate after, bf16 gather at 64) ----
  gemm_bias_b16<<<dim3(MB, 1), 256, 0, stream>>>(enc1, We2, be2, A1b, N_NODES, F1, F2);
  hipMemsetAsync(stat, 0, 512 * sizeof(float), stream);
  agg_wave_bf16_64<true><<<AGG_GRID, 256, 0, stream>>>(A1b, offs, csrS, csrW, dinv, B0f, stat);
  bn_finalize<<<1, 256, 0, stream>>>(stat, g2, bb2, scale, shift, F2);
  bn_apply2<F2, false, true, true><<<4096, 256, 0, stream>>>(B0f, scale, shift, enc2, C2b);

  // ---- Layer 3: F2 -> F1 (propagate FIRST, bf16 gather at 64) ----
  agg_wave_bf16_64<false><<<AGG_GRID, 256, 0, stream>>>(C2b, offs, csrS, csrW, dinv, A3f, stat);
  hipMemsetAsync(stat, 0, 512 * sizeof(float), stream);
  gemm_rs_relu_stats<<<dim3(MB, 2), 256, 0, stream>>>(A3f, Wd1, bd1, rowsum, B0f,
                                                      stat, N_NODES, F2, F1);
  bn_finalize<<<1, 256, 0, stream>>>(stat, g3, bb3, scale, shift, F1);
  bn_apply2<F1, true, false, true><<<4096, 256, 0, stream>>>(B0f, scale, shift, nullptr, D3b);

  // ---- Layer 4: F1 -> F0 (propagate FIRST, bf16 gather at 128) ----
  agg_wave_bf16_128<false><<<AGG_GRID, 256, 0, stream>>>(D3b, offs, csrS, csrW, dinv, A4f, stat);
  hipMemsetAsync(stat, 0, 512 * sizeof(float), stream);
  gemm_rs_relu_stats<<<dim3(MB, 4), 256, 0, stream>>>(A4f, Wd2, bd2, rowsum, B0f,
                                                      stat, N_NODES, F1, F0);
  bn_finalize<<<1, 256, 0, stream>>>(stat, g4, bb4, scale, shift, F0);
  bn_apply2<F0, false, true, false><<<4096, 256, 0, stream>>>(B0f, scale, shift, out, nullptr);
}

// Round 6
// 683.204 us; speedup vs baseline: 1.5656x; 1.0058x over previous
//
#include <hip/hip_runtime.h>

#define N_NODES 50000
#define F0 256
#define F1 128
#define F2 64
#define BN_EPS 1e-5f

typedef float f32x4 __attribute__((ext_vector_type(4)));
typedef __bf16 bf16x8 __attribute__((ext_vector_type(8)));
typedef unsigned short ushort8v __attribute__((ext_vector_type(8)));

__device__ __forceinline__ float bflo(unsigned v) { return __uint_as_float(v << 16); }
__device__ __forceinline__ float bfhi(unsigned v) { return __uint_as_float(v & 0xFFFF0000u); }
__device__ __forceinline__ unsigned short f2bf(float f) {
  unsigned u = __float_as_uint(f);
  u += 0x7FFFu + ((u >> 16) & 1u);
  return (unsigned short)(u >> 16);
}
__device__ __forceinline__ void split2(float a, unsigned short& hi, unsigned short& lo) {
  hi = f2bf(a);
  float hf = __uint_as_float((unsigned)hi << 16);
  lo = f2bf(a - hf);
}

// ---------------- CSR build ----------------
__global__ void count_dst(const int* __restrict__ dst, int* __restrict__ counts, int E) {
  int e = blockIdx.x * blockDim.x + threadIdx.x;
  if (e < E) atomicAdd(&counts[dst[e]], 1);
}

__global__ void compute_dinv(const int* __restrict__ counts, float* __restrict__ dinv) {
  int i = blockIdx.x * blockDim.x + threadIdx.x;
  if (i < N_NODES) dinv[i] = rsqrtf((float)counts[i] + 1.0f);
}

__global__ __launch_bounds__(1024) void scan_offsets(const int* __restrict__ counts,
                                                     int* __restrict__ offs) {
  __shared__ int s_wsum[16];
  __shared__ int s_carry, s_total;
  int tid = threadIdx.x;
  int lane = tid & 63, wid = tid >> 6;
  if (tid == 0) s_carry = 0;
  __syncthreads();
  for (int base = 0; base < N_NODES; base += 1024) {
    int i = base + tid;
    int v = (i < N_NODES) ? counts[i] : 0;
    int incl = v;
#pragma unroll
    for (int d = 1; d < 64; d <<= 1) {
      int t = __shfl_up(incl, d);
      if (lane >= d) incl += t;
    }
    if (lane == 63) s_wsum[wid] = incl;
    __syncthreads();
    if (tid == 0) {
      int run = 0;
      for (int j = 0; j < 16; j++) { int t = s_wsum[j]; s_wsum[j] = run; run += t; }
      s_total = run;
    }
    __syncthreads();
    if (i < N_NODES) offs[i] = s_carry + s_wsum[wid] + incl - v;
    __syncthreads();
    if (tid == 0) s_carry += s_total;
    __syncthreads();
  }
  if (tid == 0) offs[N_NODES] = s_carry;
}

__global__ void fill_csr(const int* __restrict__ src, const int* __restrict__ dst,
                         const int* __restrict__ offs, int* __restrict__ cursor,
                         const float* __restrict__ dinv,
                         int* __restrict__ csr_src, float* __restrict__ csr_w, int E) {
  int e = blockIdx.x * blockDim.x + threadIdx.x;
  if (e < E) {
    int s = src[e], d = dst[e];
    int p = offs[d] + atomicAdd(&cursor[d], 1);
    csr_src[p] = s;
    csr_w[p] = dinv[s] * dinv[d];
  }
}

__global__ void compute_rowsum(const int* __restrict__ offs, const float* __restrict__ csr_w,
                               const float* __restrict__ dinv, float* __restrict__ rowsum) {
  int i = blockIdx.x * blockDim.x + threadIdx.x;
  if (i < N_NODES) {
    float s = dinv[i] * dinv[i];
    int e1 = offs[i + 1];
    for (int e = offs[i]; e < e1; e++) s += csr_w[e];
    rowsum[i] = s;
  }
}

// ---------------- conversions (split hi/lo) ----------------
__global__ __launch_bounds__(256) void f32_to_bf16_split(const float* __restrict__ in,
                                                         unsigned short* __restrict__ hi,
                                                         unsigned short* __restrict__ lo,
                                                         int n4) {
  for (int i = blockIdx.x * blockDim.x + threadIdx.x; i < n4; i += gridDim.x * blockDim.x) {
    float4 v = ((const float4*)in)[i];
    ushort4 h, l;
    split2(v.x, h.x, l.x);
    split2(v.y, h.y, l.y);
    split2(v.z, h.z, l.z);
    split2(v.w, h.w, l.w);
    ((ushort4*)hi)[i] = h;
    ((ushort4*)lo)[i] = l;
  }
}

// W[K][N] fp32 -> Whi_t[N][K], Wlo_t[N][K] bf16
__global__ void convert_wt_split(const float* __restrict__ W,
                                 unsigned short* __restrict__ Whi,
                                 unsigned short* __restrict__ Wlo, int K, int N) {
  int idx = blockIdx.x * blockDim.x + threadIdx.x;
  if (idx < K * N) {
    int k = idx / N, n = idx - k * N;
    unsigned short h, l;
    split2(W[idx], h, l);
    Whi[(size_t)n * K + k] = h;
    Wlo[(size_t)n * K + k] = l;
  }
}

// ---------------- split-bf16 MFMA GEMM ----------------
// C = (Ahi+Alo)[M,K] @ (Whi+Wlo)[N,K]^T via 3 MFMA terms -> ~fp32 accuracy.
// BM=128, BK=32, 256 threads (4 waves).
// STATS=false: C = bf16(acc + bias[n])   -> Cb
// STATS=true : C = relu(acc + rowsum[m]*bias[n]) fp32 -> Cf, + BN stat atomics
template <int BN, bool STATS>
__global__ __launch_bounds__(256) void mfma_gemm_split(
    const unsigned short* __restrict__ Ahi, const unsigned short* __restrict__ Alo,
    const unsigned short* __restrict__ Whi, const unsigned short* __restrict__ Wlo,
    const float* __restrict__ bias, const float* __restrict__ rowsum,
    unsigned short* __restrict__ Cb, float* __restrict__ Cf,
    float* __restrict__ stat, int M, int K, int N) {
  constexpr int BM = 128;
  constexpr int MT = (BN == 128) ? 4 : 2;
  constexpr int NT = 4;
  __shared__ __align__(16) unsigned short AsH[4][BM][8];
  __shared__ __align__(16) unsigned short AsL[4][BM][8];
  __shared__ __align__(16) unsigned short BsH[4][BN][8];
  __shared__ __align__(16) unsigned short BsL[4][BN][8];
  const int tid = threadIdx.x;
  const int lane = tid & 63, wid = tid >> 6;
  const int quad = lane >> 4, ln = lane & 15;
  const int m0 = blockIdx.x * BM;
  const int n0 = blockIdx.y * BN;
  const int wm = (BN == 128) ? (wid & 1) * 64 : wid * 32;
  const int wn = (BN == 128) ? (wid >> 1) * 64 : 0;
  f32x4 acc[MT][NT] = {};

  const int arow = tid >> 2, aseg = tid & 3;
  for (int k0 = 0; k0 < K; k0 += 32) {
#pragma unroll
    for (int i = 0; i < 2; i++) {
      int row = arow + i * 64;
      int gm = m0 + row;
      ushort8v vh = {0, 0, 0, 0, 0, 0, 0, 0};
      ushort8v vl = {0, 0, 0, 0, 0, 0, 0, 0};
      if (gm < M) {
        vh = *(const ushort8v*)(Ahi + (size_t)gm * K + k0 + aseg * 8);
        vl = *(const ushort8v*)(Alo + (size_t)gm * K + k0 + aseg * 8);
      }
      *(ushort8v*)(&AsH[aseg][row][0]) = vh;
      *(ushort8v*)(&AsL[aseg][row][0]) = vl;
    }
#pragma unroll
    for (int i = 0; i < BN / 64; i++) {
      int n = arow + i * 64;
      *(ushort8v*)(&BsH[aseg][n][0]) =
          *(const ushort8v*)(Whi + (size_t)(n0 + n) * K + k0 + aseg * 8);
      *(ushort8v*)(&BsL[aseg][n][0]) =
          *(const ushort8v*)(Wlo + (size_t)(n0 + n) * K + k0 + aseg * 8);
    }
    __syncthreads();
    bf16x8 ah[MT], al[MT], bh[NT], bl[NT];
#pragma unroll
    for (int mt = 0; mt < MT; mt++) {
      ah[mt] = *(const bf16x8*)(&AsH[quad][wm + mt * 16 + ln][0]);
      al[mt] = *(const bf16x8*)(&AsL[quad][wm + mt * 16 + ln][0]);
    }
#pragma unroll
    for (int nt = 0; nt < NT; nt++) {
      bh[nt] = *(const bf16x8*)(&BsH[quad][wn + nt * 16 + ln][0]);
      bl[nt] = *(const bf16x8*)(&BsL[quad][wn + nt * 16 + ln][0]);
    }
#pragma unroll
    for (int mt = 0; mt < MT; mt++)
#pragma unroll
      for (int nt = 0; nt < NT; nt++) {
        acc[mt][nt] = __builtin_amdgcn_mfma_f32_16x16x32_bf16(ah[mt], bl[nt], acc[mt][nt], 0, 0, 0);
        acc[mt][nt] = __builtin_amdgcn_mfma_f32_16x16x32_bf16(al[mt], bh[nt], acc[mt][nt], 0, 0, 0);
        acc[mt][nt] = __builtin_amdgcn_mfma_f32_16x16x32_bf16(ah[mt], bh[nt], acc[mt][nt], 0, 0, 0);
      }
    __syncthreads();
  }

  if (!STATS) {
#pragma unroll
    for (int nt = 0; nt < NT; nt++) {
      int gn = n0 + wn + nt * 16 + ln;
      float bv = bias[gn];
#pragma unroll
      for (int mt = 0; mt < MT; mt++) {
#pragma unroll
        for (int r = 0; r < 4; r++) {
          int gm = m0 + wm + mt * 16 + quad * 4 + r;
          if (gm < M) Cb[(size_t)gm * N + gn] = f2bf(acc[mt][nt][r] + bv);
        }
      }
    }
  } else {
    float rs[MT][4];
#pragma unroll
    for (int mt = 0; mt < MT; mt++)
#pragma unroll
      for (int r = 0; r < 4; r++) {
        int gm = m0 + wm + mt * 16 + quad * 4 + r;
        rs[mt][r] = (gm < M) ? rowsum[gm] : 0.f;
      }
#pragma unroll
    for (int nt = 0; nt < NT; nt++) {
      int gn = n0 + wn + nt * 16 + ln;
      float bv = bias[gn];
      float ls = 0.f, lq = 0.f;
#pragma unroll
      for (int mt = 0; mt < MT; mt++) {
#pragma unroll
        for (int r = 0; r < 4; r++) {
          int gm = m0 + wm + mt * 16 + quad * 4 + r;
          if (gm < M) {
            float v = fmaxf(fmaf(bv, rs[mt][r], acc[mt][nt][r]), 0.f);
            Cf[(size_t)gm * N + gn] = v;
            ls += v;
            lq = fmaf(v, v, lq);
          }
        }
      }
      ls += __shfl_xor(ls, 16); ls += __shfl_xor(ls, 32);
      lq += __shfl_xor(lq, 16); lq += __shfl_xor(lq, 32);
      if (quad == 0) {
        atomicAdd(&stat[gn], ls);
        atomicAdd(&stat[256 + gn], lq);
      }
    }
  }
}

// ---------------- agg, bf16 input, F=128: one node per wave ----------------
// OUT_SPLIT=false: fp32 out (outf) [+relu+stats]; OUT_SPLIT=true: hi/lo bf16 planes
template <bool RELU_STATS, bool OUT_SPLIT>
__global__ __launch_bounds__(256) void agg_wave_bf16_128(
    const unsigned short* __restrict__ hb, const int* __restrict__ offs,
    const int* __restrict__ csr_src, const float* __restrict__ csr_w,
    const float* __restrict__ dinv, float* __restrict__ outf,
    unsigned short* __restrict__ outhi, unsigned short* __restrict__ outlo,
    float* __restrict__ stat) {
  const int tid = threadIdx.x;
  const int lane = tid & 63;
  const int widx = tid >> 6;
  const int nwaves = gridDim.x * 4;
  float ls0 = 0.f, ls1 = 0.f, lq0 = 0.f, lq1 = 0.f;

  for (int node = blockIdx.x * 4 + widx; node < N_NODES; node += nwaves) {
    const int e0 = offs[node], e1 = offs[node + 1];
    float a0 = 0.f, a1 = 0.f;
    for (int e = e0; e < e1; e += 64) {
      const int cnt = min(64, e1 - e);
      int idx = 0;
      float wt = 0.f;
      if (lane < cnt) {
        idx = csr_src[e + lane];
        wt = csr_w[e + lane];
      }
      int j = 0;
      for (; j + 8 <= cnt; j += 8) {
        int s0 = __shfl(idx, j + 0); float w0 = __shfl(wt, j + 0);
        int s1 = __shfl(idx, j + 1); float w1 = __shfl(wt, j + 1);
        int s2 = __shfl(idx, j + 2); float w2 = __shfl(wt, j + 2);
        int s3 = __shfl(idx, j + 3); float w3 = __shfl(wt, j + 3);
        int s4 = __shfl(idx, j + 4); float w4 = __shfl(wt, j + 4);
        int s5 = __shfl(idx, j + 5); float w5 = __shfl(wt, j + 5);
        int s6 = __shfl(idx, j + 6); float w6 = __shfl(wt, j + 6);
        int s7 = __shfl(idx, j + 7); float w7 = __shfl(wt, j + 7);
        unsigned v0 = *(const unsigned*)(hb + (size_t)s0 * 128 + lane * 2);
        unsigned v1 = *(const unsigned*)(hb + (size_t)s1 * 128 + lane * 2);
        unsigned v2 = *(const unsigned*)(hb + (size_t)s2 * 128 + lane * 2);
        unsigned v3 = *(const unsigned*)(hb + (size_t)s3 * 128 + lane * 2);
        unsigned v4 = *(const unsigned*)(hb + (size_t)s4 * 128 + lane * 2);
        unsigned v5 = *(const unsigned*)(hb + (size_t)s5 * 128 + lane * 2);
        unsigned v6 = *(const unsigned*)(hb + (size_t)s6 * 128 + lane * 2);
        unsigned v7 = *(const unsigned*)(hb + (size_t)s7 * 128 + lane * 2);
        a0 = fmaf(bflo(v0), w0, a0); a1 = fmaf(bfhi(v0), w0, a1);
        a0 = fmaf(bflo(v1), w1, a0); a1 = fmaf(bfhi(v1), w1, a1);
        a0 = fmaf(bflo(v2), w2, a0); a1 = fmaf(bfhi(v2), w2, a1);
        a0 = fmaf(bflo(v3), w3, a0); a1 = fmaf(bfhi(v3), w3, a1);
        a0 = fmaf(bflo(v4), w4, a0); a1 = fmaf(bfhi(v4), w4, a1);
        a0 = fmaf(bflo(v5), w5, a0); a1 = fmaf(bfhi(v5), w5, a1);
        a0 = fmaf(bflo(v6), w6, a0); a1 = fmaf(bfhi(v6), w6, a1);
        a0 = fmaf(bflo(v7), w7, a0); a1 = fmaf(bfhi(v7), w7, a1);
      }
      for (; j < cnt; j++) {
        int s = __shfl(idx, j);
        float w = __shfl(wt, j);
        unsigned v = *(const unsigned*)(hb + (size_t)s * 128 + lane * 2);
        a0 = fmaf(bflo(v), w, a0);
        a1 = fmaf(bfhi(v), w, a1);
      }
    }
    float di = dinv[node];
    float ds = di * di;
    unsigned vs = *(const unsigned*)(hb + (size_t)node * 128 + lane * 2);
    a0 = fmaf(bflo(vs), ds, a0);
    a1 = fmaf(bfhi(vs), ds, a1);
    if (RELU_STATS) {
      a0 = fmaxf(a0, 0.f);
      a1 = fmaxf(a1, 0.f);
      ls0 += a0; ls1 += a1;
      lq0 = fmaf(a0, a0, lq0);
      lq1 = fmaf(a1, a1, lq1);
    }
    if (OUT_SPLIT) {
      unsigned short h0, l0, h1, l1;
      split2(a0, h0, l0);
      split2(a1, h1, l1);
      *(unsigned*)(outhi + (size_t)node * 128 + lane * 2) = (unsigned)h0 | ((unsigned)h1 << 16);
      *(unsigned*)(outlo + (size_t)node * 128 + lane * 2) = (unsigned)l0 | ((unsigned)l1 << 16);
    } else {
      *(float2*)(outf + (size_t)node * 128 + lane * 2) = make_float2(a0, a1);
    }
  }

  if (RELU_STATS) {
    __shared__ float red[4][128];
    red[widx][lane * 2 + 0] = ls0;
    red[widx][lane * 2 + 1] = ls1;
    __syncthreads();
    if (tid < 128) {
      atomicAdd(&stat[tid], red[0][tid] + red[1][tid] + red[2][tid] + red[3][tid]);
    }
    __syncthreads();
    red[widx][lane * 2 + 0] = lq0;
    red[widx][lane * 2 + 1] = lq1;
    __syncthreads();
    if (tid < 128) {
      atomicAdd(&stat[256 + tid], red[0][tid] + red[1][tid] + red[2][tid] + red[3][tid]);
    }
  }
}

// ---------------- agg, bf16 input, F=64: one node per wave, TWO edges per gather ----------------
template <bool RELU_STATS, bool OUT_SPLIT>
__global__ __launch_bounds__(256) void agg_wave_bf16_64(
    const unsigned short* __restrict__ hb, const int* __restrict__ offs,
    const int* __restrict__ csr_src, const float* __restrict__ csr_w,
    const float* __restrict__ dinv, float* __restrict__ outf,
    unsigned short* __restrict__ outhi, unsigned short* __restrict__ outlo,
    float* __restrict__ stat) {
  const int tid = threadIdx.x;
  const int lane = tid & 63;
  const int widx = tid >> 6;
  const int half = lane >> 5;
  const int hl = lane & 31;
  const int nwaves = gridDim.x * 4;
  float ls0 = 0.f, ls1 = 0.f, lq0 = 0.f, lq1 = 0.f;

  for (int node = blockIdx.x * 4 + widx; node < N_NODES; node += nwaves) {
    const int e0 = offs[node], e1 = offs[node + 1];
    float a0 = 0.f, a1 = 0.f;
    for (int e = e0; e < e1; e += 64) {
      const int cnt = min(64, e1 - e);
      int idx = 0;
      float wt = 0.f;
      if (lane < cnt) {
        idx = csr_src[e + lane];
        wt = csr_w[e + lane];
      }
      int j = 0;
      for (; j + 16 <= cnt; j += 16) {
        int s0 = __shfl(idx, j + 0 + half);  float w0 = __shfl(wt, j + 0 + half);
        int s1 = __shfl(idx, j + 2 + half);  float w1 = __shfl(wt, j + 2 + half);
        int s2 = __shfl(idx, j + 4 + half);  float w2 = __shfl(wt, j + 4 + half);
        int s3 = __shfl(idx, j + 6 + half);  float w3 = __shfl(wt, j + 6 + half);
        int s4 = __shfl(idx, j + 8 + half);  float w4 = __shfl(wt, j + 8 + half);
        int s5 = __shfl(idx, j + 10 + half); float w5 = __shfl(wt, j + 10 + half);
        int s6 = __shfl(idx, j + 12 + half); float w6 = __shfl(wt, j + 12 + half);
        int s7 = __shfl(idx, j + 14 + half); float w7 = __shfl(wt, j + 14 + half);
        unsigned v0 = *(const unsigned*)(hb + (size_t)s0 * 64 + hl * 2);
        unsigned v1 = *(const unsigned*)(hb + (size_t)s1 * 64 + hl * 2);
        unsigned v2 = *(const unsigned*)(hb + (size_t)s2 * 64 + hl * 2);
        unsigned v3 = *(const unsigned*)(hb + (size_t)s3 * 64 + hl * 2);
        unsigned v4 = *(const unsigned*)(hb + (size_t)s4 * 64 + hl * 2);
        unsigned v5 = *(const unsigned*)(hb + (size_t)s5 * 64 + hl * 2);
        unsigned v6 = *(const unsigned*)(hb + (size_t)s6 * 64 + hl * 2);
        unsigned v7 = *(const unsigned*)(hb + (size_t)s7 * 64 + hl * 2);
        a0 = fmaf(bflo(v0), w0, a0); a1 = fmaf(bfhi(v0), w0, a1);
        a0 = fmaf(bflo(v1), w1, a0); a1 = fmaf(bfhi(v1), w1, a1);
        a0 = fmaf(bflo(v2), w2, a0); a1 = fmaf(bfhi(v2), w2, a1);
        a0 = fmaf(bflo(v3), w3, a0); a1 = fmaf(bfhi(v3), w3, a1);
        a0 = fmaf(bflo(v4), w4, a0); a1 = fmaf(bfhi(v4), w4, a1);
        a0 = fmaf(bflo(v5), w5, a0); a1 = fmaf(bfhi(v5), w5, a1);
        a0 = fmaf(bflo(v6), w6, a0); a1 = fmaf(bfhi(v6), w6, a1);
        a0 = fmaf(bflo(v7), w7, a0); a1 = fmaf(bfhi(v7), w7, a1);
      }
      for (; j + 2 <= cnt; j += 2) {
        int s = __shfl(idx, j + half);
        float w = __shfl(wt, j + half);
        unsigned v = *(const unsigned*)(hb + (size_t)s * 64 + hl * 2);
        a0 = fmaf(bflo(v), w, a0);
        a1 = fmaf(bfhi(v), w, a1);
      }
      if (j < cnt) {
        int s = __shfl(idx, j);
        float w = __shfl(wt, j);
        if (half == 0) {
          unsigned v = *(const unsigned*)(hb + (size_t)s * 64 + hl * 2);
          a0 = fmaf(bflo(v), w, a0);
          a1 = fmaf(bfhi(v), w, a1);
        }
      }
    }
    a0 += __shfl_xor(a0, 32);
    a1 += __shfl_xor(a1, 32);
    float di = dinv[node];
    float ds = di * di;
    unsigned vs = *(const unsigned*)(hb + (size_t)node * 64 + hl * 2);
    a0 = fmaf(bflo(vs), ds, a0);
    a1 = fmaf(bfhi(vs), ds, a1);
    if (RELU_STATS) {
      a0 = fmaxf(a0, 0.f);
      a1 = fmaxf(a1, 0.f);
      if (half == 0) {
        ls0 += a0; ls1 += a1;
        lq0 = fmaf(a0, a0, lq0);
        lq1 = fmaf(a1, a1, lq1);
      }
    }
    if (half == 0) {
      if (OUT_SPLIT) {
        unsigned short h0, l0, h1, l1;
        split2(a0, h0, l0);
        split2(a1, h1, l1);
        *(unsigned*)(outhi + (size_t)node * 64 + hl * 2) = (unsigned)h0 | ((unsigned)h1 << 16);
        *(unsigned*)(outlo + (size_t)node * 64 + hl * 2) = (unsigned)l0 | ((unsigned)l1 << 16);
      } else {
        *(float2*)(outf + (size_t)node * 64 + hl * 2) = make_float2(a0, a1);
      }
    }
  }

  if (RELU_STATS) {
    __shared__ float red[4][64];
    if (half == 0) {
      red[widx][hl * 2 + 0] = ls0;
      red[widx][hl * 2 + 1] = ls1;
    }
    __syncthreads();
    if (tid < 64) {
      atomicAdd(&stat[tid], red[0][tid] + red[1][tid] + red[2][tid] + red[3][tid]);
    }
    __syncthreads();
    if (half == 0) {
      red[widx][hl * 2 + 0] = lq0;
      red[widx][hl * 2 + 1] = lq1;
    }
    __syncthreads();
    if (tid < 64) {
      atomicAdd(&stat[256 + tid], red[0][tid] + red[1][tid] + red[2][tid] + red[3][tid]);
    }
  }
}

// ---------------- BN finalize ----------------
__global__ void bn_finalize(const float* __restrict__ stat, const float* __restrict__ g,
                            const float* __restrict__ bb, float* __restrict__ scale,
                            float* __restrict__ shift, int F) {
  int c = threadIdx.x;
  if (c < F) {
    const float invN = 1.0f / (float)N_NODES;
    float mean = stat[c] * invN;
    float var = stat[256 + c] * invN - mean * mean;
    var = fmaxf(var, 0.f);
    float inv = rsqrtf(var + BN_EPS);
    float sc = g[c] * inv;
    scale[c] = sc;
    shift[c] = bb[c] - mean * sc;
  }
}

// ---------------- BN apply: fp32 / single-bf16 / split-bf16 outputs ----------------
template <int F, bool RELU, bool WF32, bool WB16, bool WSPLIT>
__global__ __launch_bounds__(256) void bn_apply3(const float* __restrict__ a,
                                                 const float* __restrict__ scale,
                                                 const float* __restrict__ shift,
                                                 float* __restrict__ outf,
                                                 unsigned short* __restrict__ outb,
                                                 unsigned short* __restrict__ outhi,
                                                 unsigned short* __restrict__ outlo) {
  constexpr int C4 = F / 4;
  const int total = N_NODES * C4;
  for (int idx = blockIdx.x * blockDim.x + threadIdx.x; idx < total;
       idx += gridDim.x * blockDim.x) {
    int c4 = idx % C4;
    float4 v = ((const float4*)a)[idx];
    float4 s = ((const float4*)scale)[c4];
    float4 sh = ((const float4*)shift)[c4];
    float4 o;
    o.x = fmaf(v.x, s.x, sh.x);
    o.y = fmaf(v.y, s.y, sh.y);
    o.z = fmaf(v.z, s.z, sh.z);
    o.w = fmaf(v.w, s.w, sh.w);
    if (RELU) {
      o.x = fmaxf(o.x, 0.f);
      o.y = fmaxf(o.y, 0.f);
      o.z = fmaxf(o.z, 0.f);
      o.w = fmaxf(o.w, 0.f);
    }
    if (WF32) ((float4*)outf)[idx] = o;
    if (WB16) {
      ushort4 b;
      b.x = f2bf(o.x); b.y = f2bf(o.y); b.z = f2bf(o.z); b.w = f2bf(o.w);
      ((ushort4*)outb)[idx] = b;
    }
    if (WSPLIT) {
      ushort4 h, l;
      split2(o.x, h.x, l.x);
      split2(o.y, h.y, l.y);
      split2(o.z, h.z, l.z);
      split2(o.w, h.w, l.w);
      ((ushort4*)outhi)[idx] = h;
      ((ushort4*)outlo)[idx] = l;
    }
  }
}

extern "C" void kernel_launch(void* const* d_in, const int* in_sizes, int n_in,
                              void* d_out, int out_size, void* d_ws, size_t ws_size,
                              hipStream_t stream) {
  const float* x = (const float*)d_in[0];
  const int* ei = (const int*)d_in[1];
  const int E = in_sizes[1] / 2;
  const int* src = ei;
  const int* dst = ei + E;
  const float* We1 = (const float*)d_in[2];  const float* be1 = (const float*)d_in[3];
  const float* g1  = (const float*)d_in[4];  const float* bb1 = (const float*)d_in[5];
  const float* We2 = (const float*)d_in[6];  const float* be2 = (const float*)d_in[7];
  const float* g2  = (const float*)d_in[8];  const float* bb2 = (const float*)d_in[9];
  const float* Wd1 = (const float*)d_in[10]; const float* bd1 = (const float*)d_in[11];
  const float* g3  = (const float*)d_in[12]; const float* bb3 = (const float*)d_in[13];
  const float* Wd2 = (const float*)d_in[14]; const float* bd2 = (const float*)d_in[15];
  const float* g4  = (const float*)d_in[16]; const float* bb4 = (const float*)d_in[17];

  float* out = (float*)d_out;
  char* ws = (char*)d_ws;
  // Region A [0, 51.2MB) — disjoint lifetimes verified per step:
  unsigned short* xhi  = (unsigned short*)(ws + 0);         // steps 1-2 (25.6M)
  unsigned short* xlo  = (unsigned short*)(ws + 51200000);  // steps 1-2 (borrows B0f region)
  unsigned short* A0b  = (unsigned short*)(ws + 76800000);  // steps 2-3 (12.8M)
  unsigned short* E1hi = (unsigned short*)(ws + 0);         // steps 4-5 (12.8M)
  unsigned short* E1lo = (unsigned short*)(ws + 12800000);  // steps 4-5 (12.8M)
  unsigned short* A1b  = (unsigned short*)(ws + 25600000);  // steps 5-6 (6.4M)
  unsigned short* C2b  = (unsigned short*)(ws + 32000000);  // steps 7-8 (6.4M)
  unsigned short* G3hi = (unsigned short*)(ws + 0);         // steps 8-9 (6.4M)
  unsigned short* G3lo = (unsigned short*)(ws + 6400000);   // steps 8-9 (6.4M)
  unsigned short* D3b  = (unsigned short*)(ws + 12800000);  // steps 10-11 (12.8M)
  unsigned short* G4hi = (unsigned short*)(ws + 0);         // steps 11-12 (12.8M)
  unsigned short* G4lo = (unsigned short*)(ws + 25600000);  // steps 11-12 (12.8M)
  unsigned short* Wb   = (unsigned short*)(ws + 48000000);  // weights, persist (0.33M)
  unsigned short* W1h = Wb;            unsigned short* W1l = W1h + 32768;
  unsigned short* W2h = W1l + 32768;   unsigned short* W2l = W2h + 8192;
  unsigned short* W3h = W2l + 8192;    unsigned short* W3l = W3h + 8192;
  unsigned short* W4h = W3l + 8192;    unsigned short* W4l = W4h + 32768;
  float* B0f  = (float*)(ws + 51200000);  // pre-BN fp32 (up to 51.2M at L4)
  int*   csrS   = (int*)(ws + 102400000);
  float* csrW   = (float*)(ws + 105600000);
  int*   counts = (int*)(ws + 108800000);
  int*   cursor = (int*)(ws + 109000000);
  int*   offs   = (int*)(ws + 109200000);
  float* dinv   = (float*)(ws + 109400064);
  float* stat   = (float*)(ws + 109600064);
  float* scale  = (float*)(ws + 109602112);
  float* shift  = (float*)(ws + 109603136);
  if (ws_size < 109604160) return;
  float* rowsum = (float*)cursor;

  float* enc1 = out + (size_t)N_NODES * F0;
  float* enc2 = enc1 + (size_t)N_NODES * F1;

  const int EB = (E + 255) / 256;
  const int AGG_GRID = 2048;
  const int MB = (N_NODES + 127) / 128;  // 391

  // step 1: conversions
  f32_to_bf16_split<<<4096, 256, 0, stream>>>(x, xhi, xlo, N_NODES * F0 / 4);
  convert_wt_split<<<(F0 * F1 + 255) / 256, 256, 0, stream>>>(We1, W1h, W1l, F0, F1);
  convert_wt_split<<<(F1 * F2 + 255) / 256, 256, 0, stream>>>(We2, W2h, W2l, F1, F2);
  convert_wt_split<<<(F2 * F1 + 255) / 256, 256, 0, stream>>>(Wd1, W3h, W3l, F2, F1);
  convert_wt_split<<<(F1 * F0 + 255) / 256, 256, 0, stream>>>(Wd2, W4h, W4l, F1, F0);

  // CSR build + normalization constants
  hipMemsetAsync(counts, 0, 2 * N_NODES * sizeof(int), stream);
  count_dst<<<EB, 256, 0, stream>>>(dst, counts, E);
  compute_dinv<<<(N_NODES + 255) / 256, 256, 0, stream>>>(counts, dinv);
  scan_offsets<<<1, 1024, 0, stream>>>(counts, offs);
  fill_csr<<<EB, 256, 0, stream>>>(src, dst, offs, cursor, dinv, csrS, csrW, E);
  compute_rowsum<<<(N_NODES + 255) / 256, 256, 0, stream>>>(offs, csrW, dinv, rowsum);

  // ---- Layer 1: F0 -> F1 (propagate after) ----
  mfma_gemm_split<128, false><<<dim3(MB, 1), 256, 0, stream>>>(
      xhi, xlo, W1h, W1l, be1, nullptr, A0b, nullptr, nullptr, N_NODES, F0, F1);
  hipMemsetAsync(stat, 0, 512 * sizeof(float), stream);
  agg_wave_bf16_128<true, false><<<AGG_GRID, 256, 0, stream>>>(
      A0b, offs, csrS, csrW, dinv, B0f, nullptr, nullptr, stat);
  bn_finalize<<<1, 256, 0, stream>>>(stat, g1, bb1, scale, shift, F1);
  bn_apply3<F1, true, true, false, true><<<4096, 256, 0, stream>>>(
      B0f, scale, shift, enc1, nullptr, E1hi, E1lo);

  // ---- Layer 2: F1 -> F2 (propagate after) ----
  mfma_gemm_split<64, false><<<dim3(MB, 1), 256, 0, stream>>>(
      E1hi, E1lo, W2h, W2l, be2, nullptr, A1b, nullptr, nullptr, N_NODES, F1, F2);
  hipMemsetAsync(stat, 0, 512 * sizeof(float), stream);
  agg_wave_bf16_64<true, false><<<AGG_GRID, 256, 0, stream>>>(
      A1b, offs, csrS, csrW, dinv, B0f, nullptr, nullptr, stat);
  bn_finalize<<<1, 256, 0, stream>>>(stat, g2, bb2, scale, shift, F2);
  bn_apply3<F2, false, true, true, false><<<4096, 256, 0, stream>>>(
      B0f, scale, shift, enc2, C2b, nullptr, nullptr);

  // ---- Layer 3: F2 -> F1 (propagate FIRST) ----
  agg_wave_bf16_64<false, true><<<AGG_GRID, 256, 0, stream>>>(
      C2b, offs, csrS, csrW, dinv, nullptr, G3hi, G3lo, stat);
  hipMemsetAsync(stat, 0, 512 * sizeof(float), stream);
  mfma_gemm_split<128, true><<<dim3(MB, 1), 256, 0, stream>>>(
      G3hi, G3lo, W3h, W3l, bd1, rowsum, nullptr, B0f, stat, N_NODES, F2, F1);
  bn_finalize<<<1, 256, 0, stream>>>(stat, g3, bb3, scale, shift, F1);
  bn_apply3<F1, true, false, true, false><<<4096, 256, 0, stream>>>(
      B0f, scale, shift, nullptr, D3b, nullptr, nullptr);

  // ---- Layer 4: F1 -> F0 (propagate FIRST) ----
  agg_wave_bf16_128<false, true><<<AGG_GRID, 256, 0, stream>>>(
      D3b, offs, csrS, csrW, dinv, nullptr, G4hi, G4lo, stat);
  hipMemsetAsync(stat, 0, 512 * sizeof(float), stream);
  mfma_gemm_split<128, true><<<dim3(MB, 2), 256, 0, stream>>>(
      G4hi, G4lo, W4h, W4l, bd2, rowsum, nullptr, B0f, stat, N_NODES, F1, F0);
  bn_finalize<<<1, 256, 0, stream>>>(stat, g4, bb4, scale, shift, F0);
  bn_apply3<F0, false, true, false, false><<<4096, 256, 0, stream>>>(
      B0f, scale, shift, out, nullptr, nullptr, nullptr);
}

// Round 7
// 649.440 us; speedup vs baseline: 1.6470x; 1.0520x over previous
//
#include <hip/hip_runtime.h>

#define N_NODES 50000
#define F0 256
#define F1 128
#define F2 64
#define BN_EPS 1e-5f

typedef float f32x4 __attribute__((ext_vector_type(4)));
typedef __bf16 bf16x8 __attribute__((ext_vector_type(8)));
typedef unsigned short ushort8v __attribute__((ext_vector_type(8)));

__device__ __forceinline__ float bflo(unsigned v) { return __uint_as_float(v << 16); }
__device__ __forceinline__ float bfhi(unsigned v) { return __uint_as_float(v & 0xFFFF0000u); }
__device__ __forceinline__ unsigned short f2bf(float f) {
  unsigned u = __float_as_uint(f);
  u += 0x7FFFu + ((u >> 16) & 1u);
  return (unsigned short)(u >> 16);
}
__device__ __forceinline__ void split2(float a, unsigned short& hi, unsigned short& lo) {
  hi = f2bf(a);
  float hf = __uint_as_float((unsigned)hi << 16);
  lo = f2bf(a - hf);
}
__device__ __forceinline__ int rdl(int v, int l) { return __builtin_amdgcn_readlane(v, l); }
__device__ __forceinline__ float rdlf(float v, int l) {
  return __uint_as_float((unsigned)__builtin_amdgcn_readlane(__float_as_int(v), l));
}

// ---------------- CSR build ----------------
__global__ void count_dst(const int* __restrict__ dst, int* __restrict__ counts, int E) {
  int e = blockIdx.x * blockDim.x + threadIdx.x;
  if (e < E) atomicAdd(&counts[dst[e]], 1);
}

__global__ void compute_dinv(const int* __restrict__ counts, float* __restrict__ dinv) {
  int i = blockIdx.x * blockDim.x + threadIdx.x;
  if (i < N_NODES) dinv[i] = rsqrtf((float)counts[i] + 1.0f);
}

__global__ __launch_bounds__(1024) void scan_offsets(const int* __restrict__ counts,
                                                     int* __restrict__ offs) {
  __shared__ int s_wsum[16];
  __shared__ int s_carry, s_total;
  int tid = threadIdx.x;
  int lane = tid & 63, wid = tid >> 6;
  if (tid == 0) s_carry = 0;
  __syncthreads();
  for (int base = 0; base < N_NODES; base += 1024) {
    int i = base + tid;
    int v = (i < N_NODES) ? counts[i] : 0;
    int incl = v;
#pragma unroll
    for (int d = 1; d < 64; d <<= 1) {
      int t = __shfl_up(incl, d);
      if (lane >= d) incl += t;
    }
    if (lane == 63) s_wsum[wid] = incl;
    __syncthreads();
    if (tid == 0) {
      int run = 0;
      for (int j = 0; j < 16; j++) { int t = s_wsum[j]; s_wsum[j] = run; run += t; }
      s_total = run;
    }
    __syncthreads();
    if (i < N_NODES) offs[i] = s_carry + s_wsum[wid] + incl - v;
    __syncthreads();
    if (tid == 0) s_carry += s_total;
    __syncthreads();
  }
  if (tid == 0) offs[N_NODES] = s_carry;
}

__global__ void fill_csr(const int* __restrict__ src, const int* __restrict__ dst,
                         const int* __restrict__ offs, int* __restrict__ cursor,
                         const float* __restrict__ dinv,
                         int* __restrict__ csr_src, float* __restrict__ csr_w, int E) {
  int e = blockIdx.x * blockDim.x + threadIdx.x;
  if (e < E) {
    int s = src[e], d = dst[e];
    int p = offs[d] + atomicAdd(&cursor[d], 1);
    csr_src[p] = s;
    csr_w[p] = dinv[s] * dinv[d];
  }
}

__global__ void compute_rowsum(const int* __restrict__ offs, const float* __restrict__ csr_w,
                               const float* __restrict__ dinv, float* __restrict__ rowsum) {
  int i = blockIdx.x * blockDim.x + threadIdx.x;
  if (i < N_NODES) {
    float s = dinv[i] * dinv[i];
    int e1 = offs[i + 1];
    for (int e = offs[i]; e < e1; e++) s += csr_w[e];
    rowsum[i] = s;
  }
}

// ---------------- merged weight conversion: W[K][N] fp32 -> hi/lo [N][K] bf16 ----------------
__device__ __forceinline__ void wt_one(const float* W, unsigned short* Wh, unsigned short* Wl,
                                       int K, int N, int idx) {
  int k = idx / N, n = idx - k * N;
  unsigned short h, l;
  split2(W[idx], h, l);
  Wh[(size_t)n * K + k] = h;
  Wl[(size_t)n * K + k] = l;
}

__global__ void convert_weights(const float* __restrict__ We1, const float* __restrict__ We2,
                                const float* __restrict__ Wd1, const float* __restrict__ Wd2,
                                unsigned short* W1h, unsigned short* W1l,
                                unsigned short* W2h, unsigned short* W2l,
                                unsigned short* W3h, unsigned short* W3l,
                                unsigned short* W4h, unsigned short* W4l) {
  int idx = blockIdx.x * blockDim.x + threadIdx.x;
  if (idx < 32768) {
    wt_one(We1, W1h, W1l, 256, 128, idx);
  } else if (idx < 40960) {
    wt_one(We2, W2h, W2l, 128, 64, idx - 32768);
  } else if (idx < 49152) {
    wt_one(Wd1, W3h, W3l, 64, 128, idx - 40960);
  } else if (idx < 81920) {
    wt_one(Wd2, W4h, W4l, 128, 256, idx - 49152);
  }
}

// ---------------- split-bf16 MFMA GEMM ----------------
// AF32=true: A is fp32, split hi/lo in staging. Else A given as hi/lo bf16 planes.
// STATS=false: C = bf16(acc + bias[n]) -> Cb
// STATS=true : C = relu(acc + rowsum[m]*bias[n]) fp32 -> Cf, + BN stat atomics
template <int BN, bool STATS, bool AF32>
__global__ __launch_bounds__(256) void mfma_gemm_split(
    const unsigned short* __restrict__ Ahi, const unsigned short* __restrict__ Alo,
    const float* __restrict__ Af,
    const unsigned short* __restrict__ Whi, const unsigned short* __restrict__ Wlo,
    const float* __restrict__ bias, const float* __restrict__ rowsum,
    unsigned short* __restrict__ Cb, float* __restrict__ Cf,
    float* __restrict__ stat, int M, int K, int N) {
  constexpr int BM = 128;
  constexpr int MT = (BN == 128) ? 4 : 2;
  constexpr int NT = 4;
  __shared__ __align__(16) unsigned short AsH[4][BM][8];
  __shared__ __align__(16) unsigned short AsL[4][BM][8];
  __shared__ __align__(16) unsigned short BsH[4][BN][8];
  __shared__ __align__(16) unsigned short BsL[4][BN][8];
  const int tid = threadIdx.x;
  const int lane = tid & 63, wid = tid >> 6;
  const int quad = lane >> 4, ln = lane & 15;
  const int m0 = blockIdx.x * BM;
  const int n0 = blockIdx.y * BN;
  const int wm = (BN == 128) ? (wid & 1) * 64 : wid * 32;
  const int wn = (BN == 128) ? (wid >> 1) * 64 : 0;
  f32x4 acc[MT][NT] = {};

  const int arow = tid >> 2, aseg = tid & 3;
  for (int k0 = 0; k0 < K; k0 += 32) {
#pragma unroll
    for (int i = 0; i < 2; i++) {
      int row = arow + i * 64;
      int gm = m0 + row;
      if (AF32) {
        float4 u0 = make_float4(0.f, 0.f, 0.f, 0.f), u1 = u0;
        if (gm < M) {
          u0 = *(const float4*)(Af + (size_t)gm * K + k0 + aseg * 8);
          u1 = *(const float4*)(Af + (size_t)gm * K + k0 + aseg * 8 + 4);
        }
        ushort4 h0, l0, h1, l1;
        split2(u0.x, h0.x, l0.x); split2(u0.y, h0.y, l0.y);
        split2(u0.z, h0.z, l0.z); split2(u0.w, h0.w, l0.w);
        split2(u1.x, h1.x, l1.x); split2(u1.y, h1.y, l1.y);
        split2(u1.z, h1.z, l1.z); split2(u1.w, h1.w, l1.w);
        *(ushort4*)(&AsH[aseg][row][0]) = h0;
        *(ushort4*)(&AsH[aseg][row][4]) = h1;
        *(ushort4*)(&AsL[aseg][row][0]) = l0;
        *(ushort4*)(&AsL[aseg][row][4]) = l1;
      } else {
        ushort8v vh = {0, 0, 0, 0, 0, 0, 0, 0};
        ushort8v vl = {0, 0, 0, 0, 0, 0, 0, 0};
        if (gm < M) {
          vh = *(const ushort8v*)(Ahi + (size_t)gm * K + k0 + aseg * 8);
          vl = *(const ushort8v*)(Alo + (size_t)gm * K + k0 + aseg * 8);
        }
        *(ushort8v*)(&AsH[aseg][row][0]) = vh;
        *(ushort8v*)(&AsL[aseg][row][0]) = vl;
      }
    }
#pragma unroll
    for (int i = 0; i < BN / 64; i++) {
      int n = arow + i * 64;
      *(ushort8v*)(&BsH[aseg][n][0]) =
          *(const ushort8v*)(Whi + (size_t)(n0 + n) * K + k0 + aseg * 8);
      *(ushort8v*)(&BsL[aseg][n][0]) =
          *(const ushort8v*)(Wlo + (size_t)(n0 + n) * K + k0 + aseg * 8);
    }
    __syncthreads();
    bf16x8 ah[MT], al[MT], bh[NT], bl[NT];
#pragma unroll
    for (int mt = 0; mt < MT; mt++) {
      ah[mt] = *(const bf16x8*)(&AsH[quad][wm + mt * 16 + ln][0]);
      al[mt] = *(const bf16x8*)(&AsL[quad][wm + mt * 16 + ln][0]);
    }
#pragma unroll
    for (int nt = 0; nt < NT; nt++) {
      bh[nt] = *(const bf16x8*)(&BsH[quad][wn + nt * 16 + ln][0]);
      bl[nt] = *(const bf16x8*)(&BsL[quad][wn + nt * 16 + ln][0]);
    }
#pragma unroll
    for (int mt = 0; mt < MT; mt++)
#pragma unroll
      for (int nt = 0; nt < NT; nt++) {
        acc[mt][nt] = __builtin_amdgcn_mfma_f32_16x16x32_bf16(ah[mt], bl[nt], acc[mt][nt], 0, 0, 0);
        acc[mt][nt] = __builtin_amdgcn_mfma_f32_16x16x32_bf16(al[mt], bh[nt], acc[mt][nt], 0, 0, 0);
        acc[mt][nt] = __builtin_amdgcn_mfma_f32_16x16x32_bf16(ah[mt], bh[nt], acc[mt][nt], 0, 0, 0);
      }
    __syncthreads();
  }

  if (!STATS) {
#pragma unroll
    for (int nt = 0; nt < NT; nt++) {
      int gn = n0 + wn + nt * 16 + ln;
      float bv = bias[gn];
#pragma unroll
      for (int mt = 0; mt < MT; mt++) {
#pragma unroll
        for (int r = 0; r < 4; r++) {
          int gm = m0 + wm + mt * 16 + quad * 4 + r;
          if (gm < M) Cb[(size_t)gm * N + gn] = f2bf(acc[mt][nt][r] + bv);
        }
      }
    }
  } else {
    float rs[MT][4];
#pragma unroll
    for (int mt = 0; mt < MT; mt++)
#pragma unroll
      for (int r = 0; r < 4; r++) {
        int gm = m0 + wm + mt * 16 + quad * 4 + r;
        rs[mt][r] = (gm < M) ? rowsum[gm] : 0.f;
      }
#pragma unroll
    for (int nt = 0; nt < NT; nt++) {
      int gn = n0 + wn + nt * 16 + ln;
      float bv = bias[gn];
      float ls = 0.f, lq = 0.f;
#pragma unroll
      for (int mt = 0; mt < MT; mt++) {
#pragma unroll
        for (int r = 0; r < 4; r++) {
          int gm = m0 + wm + mt * 16 + quad * 4 + r;
          if (gm < M) {
            float v = fmaxf(fmaf(bv, rs[mt][r], acc[mt][nt][r]), 0.f);
            Cf[(size_t)gm * N + gn] = v;
            ls += v;
            lq = fmaf(v, v, lq);
          }
        }
      }
      ls += __shfl_xor(ls, 16); ls += __shfl_xor(ls, 32);
      lq += __shfl_xor(lq, 16); lq += __shfl_xor(lq, 32);
      if (quad == 0) {
        atomicAdd(&stat[gn], ls);
        atomicAdd(&stat[256 + gn], lq);
      }
    }
  }
}

// ---------------- agg F=128, readlane broadcast, one node per wave ----------------
template <bool RELU_STATS, bool OUT_SPLIT>
__global__ __launch_bounds__(256) void agg128_rl(
    const unsigned short* __restrict__ hb, const int* __restrict__ offs,
    const int* __restrict__ csr_src, const float* __restrict__ csr_w,
    const float* __restrict__ dinv, float* __restrict__ outf,
    unsigned short* __restrict__ outhi, unsigned short* __restrict__ outlo,
    float* __restrict__ stat) {
  const int tid = threadIdx.x;
  const int lane = tid & 63;
  const int widx = tid >> 6;
  const int nwaves = gridDim.x * 4;
  float ls0 = 0.f, ls1 = 0.f, lq0 = 0.f, lq1 = 0.f;

  for (int node = blockIdx.x * 4 + widx; node < N_NODES; node += nwaves) {
    const int e0 = __builtin_amdgcn_readfirstlane(offs[node]);
    const int e1 = __builtin_amdgcn_readfirstlane(offs[node + 1]);
    float a0 = 0.f, a1 = 0.f;
    for (int e = e0; e < e1; e += 64) {
      const int cnt = min(64, e1 - e);
      int idx = 0;
      float wt = 0.f;
      if (lane < cnt) {
        idx = csr_src[e + lane];
        wt = csr_w[e + lane];
      }
      const int nb = (cnt + 7) & ~7;
      for (int j = 0; j < nb; j += 8) {
#pragma unroll
        for (int u = 0; u < 8; u++) {
          int s = rdl(idx, j + u);
          float w = rdlf(wt, j + u);
          unsigned v = *(const unsigned*)(hb + (size_t)s * 128 + lane * 2);
          a0 = fmaf(bflo(v), w, a0);
          a1 = fmaf(bfhi(v), w, a1);
        }
      }
    }
    float di = dinv[node];
    float ds = di * di;
    unsigned vs = *(const unsigned*)(hb + (size_t)node * 128 + lane * 2);
    a0 = fmaf(bflo(vs), ds, a0);
    a1 = fmaf(bfhi(vs), ds, a1);
    if (RELU_STATS) {
      a0 = fmaxf(a0, 0.f);
      a1 = fmaxf(a1, 0.f);
      ls0 += a0; ls1 += a1;
      lq0 = fmaf(a0, a0, lq0);
      lq1 = fmaf(a1, a1, lq1);
    }
    if (OUT_SPLIT) {
      unsigned short h0, l0, h1, l1;
      split2(a0, h0, l0);
      split2(a1, h1, l1);
      *(unsigned*)(outhi + (size_t)node * 128 + lane * 2) = (unsigned)h0 | ((unsigned)h1 << 16);
      *(unsigned*)(outlo + (size_t)node * 128 + lane * 2) = (unsigned)l0 | ((unsigned)l1 << 16);
    } else {
      *(float2*)(outf + (size_t)node * 128 + lane * 2) = make_float2(a0, a1);
    }
  }

  if (RELU_STATS) {
    __shared__ float red[4][128];
    red[widx][lane * 2 + 0] = ls0;
    red[widx][lane * 2 + 1] = ls1;
    __syncthreads();
    if (tid < 128) {
      atomicAdd(&stat[tid], red[0][tid] + red[1][tid] + red[2][tid] + red[3][tid]);
    }
    __syncthreads();
    red[widx][lane * 2 + 0] = lq0;
    red[widx][lane * 2 + 1] = lq1;
    __syncthreads();
    if (tid < 128) {
      atomicAdd(&stat[256 + tid], red[0][tid] + red[1][tid] + red[2][tid] + red[3][tid]);
    }
  }
}

// ---------------- agg F=64, readlane broadcast, two edges per gather ----------------
template <bool RELU_STATS, bool OUT_SPLIT>
__global__ __launch_bounds__(256) void agg64_rl(
    const unsigned short* __restrict__ hb, const int* __restrict__ offs,
    const int* __restrict__ csr_src, const float* __restrict__ csr_w,
    const float* __restrict__ dinv, float* __restrict__ outf,
    unsigned short* __restrict__ outhi, unsigned short* __restrict__ outlo,
    float* __restrict__ stat) {
  const int tid = threadIdx.x;
  const int lane = tid & 63;
  const int widx = tid >> 6;
  const int half = lane >> 5;
  const int hl = lane & 31;
  const int nwaves = gridDim.x * 4;
  float ls0 = 0.f, ls1 = 0.f, lq0 = 0.f, lq1 = 0.f;

  for (int node = blockIdx.x * 4 + widx; node < N_NODES; node += nwaves) {
    const int e0 = __builtin_amdgcn_readfirstlane(offs[node]);
    const int e1 = __builtin_amdgcn_readfirstlane(offs[node + 1]);
    float a0 = 0.f, a1 = 0.f;
    for (int e = e0; e < e1; e += 64) {
      const int cnt = min(64, e1 - e);
      int idx = 0;
      float wt = 0.f;
      if (lane < cnt) {
        idx = csr_src[e + lane];
        wt = csr_w[e + lane];
      }
      const int nb = (cnt + 15) & ~15;
      for (int j = 0; j < nb; j += 16) {
#pragma unroll
        for (int u = 0; u < 8; u++) {
          int sa = rdl(idx, j + 2 * u);
          int sb = rdl(idx, j + 2 * u + 1);
          float wa = rdlf(wt, j + 2 * u);
          float wb = rdlf(wt, j + 2 * u + 1);
          const unsigned short* pa = hb + (size_t)sa * 64;
          const unsigned short* pb = hb + (size_t)sb * 64;
          const unsigned short* p = half ? pb : pa;
          float w = half ? wb : wa;
          unsigned v = *(const unsigned*)(p + hl * 2);
          a0 = fmaf(bflo(v), w, a0);
          a1 = fmaf(bfhi(v), w, a1);
        }
      }
    }
    a0 += __shfl_xor(a0, 32);
    a1 += __shfl_xor(a1, 32);
    float di = dinv[node];
    float ds = di * di;
    unsigned vs = *(const unsigned*)(hb + (size_t)node * 64 + hl * 2);
    a0 = fmaf(bflo(vs), ds, a0);
    a1 = fmaf(bfhi(vs), ds, a1);
    if (RELU_STATS) {
      a0 = fmaxf(a0, 0.f);
      a1 = fmaxf(a1, 0.f);
      if (half == 0) {
        ls0 += a0; ls1 += a1;
        lq0 = fmaf(a0, a0, lq0);
        lq1 = fmaf(a1, a1, lq1);
      }
    }
    if (half == 0) {
      if (OUT_SPLIT) {
        unsigned short h0, l0, h1, l1;
        split2(a0, h0, l0);
        split2(a1, h1, l1);
        *(unsigned*)(outhi + (size_t)node * 64 + hl * 2) = (unsigned)h0 | ((unsigned)h1 << 16);
        *(unsigned*)(outlo + (size_t)node * 64 + hl * 2) = (unsigned)l0 | ((unsigned)l1 << 16);
      } else {
        *(float2*)(outf + (size_t)node * 64 + hl * 2) = make_float2(a0, a1);
      }
    }
  }

  if (RELU_STATS) {
    __shared__ float red[4][64];
    if (half == 0) {
      red[widx][hl * 2 + 0] = ls0;
      red[widx][hl * 2 + 1] = ls1;
    }
    __syncthreads();
    if (tid < 64) {
      atomicAdd(&stat[tid], red[0][tid] + red[1][tid] + red[2][tid] + red[3][tid]);
    }
    __syncthreads();
    if (half == 0) {
      red[widx][hl * 2 + 0] = lq0;
      red[widx][hl * 2 + 1] = lq1;
    }
    __syncthreads();
    if (tid < 64) {
      atomicAdd(&stat[256 + tid], red[0][tid] + red[1][tid] + red[2][tid] + red[3][tid]);
    }
  }
}

// ---------------- BN apply with inline finalize ----------------
template <int F, bool RELU, bool WF32, bool WB16, bool WSPLIT>
__global__ __launch_bounds__(256) void bn_apply_f(const float* __restrict__ a,
                                                  const float* __restrict__ stat,
                                                  const float* __restrict__ g,
                                                  const float* __restrict__ bb,
                                                  float* __restrict__ outf,
                                                  unsigned short* __restrict__ outb,
                                                  unsigned short* __restrict__ outhi,
                                                  unsigned short* __restrict__ outlo) {
  __shared__ float s_scale[F], s_shift[F];
  const int tid = threadIdx.x;
  if (tid < F) {
    const float invN = 1.0f / (float)N_NODES;
    float mean = stat[tid] * invN;
    float var = fmaxf(stat[256 + tid] * invN - mean * mean, 0.f);
    float inv = rsqrtf(var + BN_EPS);
    float sc = g[tid] * inv;
    s_scale[tid] = sc;
    s_shift[tid] = bb[tid] - mean * sc;
  }
  __syncthreads();
  constexpr int C4 = F / 4;
  const int total = N_NODES * C4;
  for (int idx = blockIdx.x * blockDim.x + tid; idx < total; idx += gridDim.x * blockDim.x) {
    int c4 = idx % C4;
    float4 v = ((const float4*)a)[idx];
    float4 s = *(float4*)&s_scale[c4 * 4];
    float4 sh = *(float4*)&s_shift[c4 * 4];
    float4 o;
    o.x = fmaf(v.x, s.x, sh.x);
    o.y = fmaf(v.y, s.y, sh.y);
    o.z = fmaf(v.z, s.z, sh.z);
    o.w = fmaf(v.w, s.w, sh.w);
    if (RELU) {
      o.x = fmaxf(o.x, 0.f);
      o.y = fmaxf(o.y, 0.f);
      o.z = fmaxf(o.z, 0.f);
      o.w = fmaxf(o.w, 0.f);
    }
    if (WF32) ((float4*)outf)[idx] = o;
    if (WB16) {
      ushort4 b;
      b.x = f2bf(o.x); b.y = f2bf(o.y); b.z = f2bf(o.z); b.w = f2bf(o.w);
      ((ushort4*)outb)[idx] = b;
    }
    if (WSPLIT) {
      ushort4 h, l;
      split2(o.x, h.x, l.x);
      split2(o.y, h.y, l.y);
      split2(o.z, h.z, l.z);
      split2(o.w, h.w, l.w);
      ((ushort4*)outhi)[idx] = h;
      ((ushort4*)outlo)[idx] = l;
    }
  }
}

extern "C" void kernel_launch(void* const* d_in, const int* in_sizes, int n_in,
                              void* d_out, int out_size, void* d_ws, size_t ws_size,
                              hipStream_t stream) {
  const float* x = (const float*)d_in[0];
  const int* ei = (const int*)d_in[1];
  const int E = in_sizes[1] / 2;
  const int* src = ei;
  const int* dst = ei + E;
  const float* We1 = (const float*)d_in[2];  const float* be1 = (const float*)d_in[3];
  const float* g1  = (const float*)d_in[4];  const float* bb1 = (const float*)d_in[5];
  const float* We2 = (const float*)d_in[6];  const float* be2 = (const float*)d_in[7];
  const float* g2  = (const float*)d_in[8];  const float* bb2 = (const float*)d_in[9];
  const float* Wd1 = (const float*)d_in[10]; const float* bd1 = (const float*)d_in[11];
  const float* g3  = (const float*)d_in[12]; const float* bb3 = (const float*)d_in[13];
  const float* Wd2 = (const float*)d_in[14]; const float* bd2 = (const float*)d_in[15];
  const float* g4  = (const float*)d_in[16]; const float* bb4 = (const float*)d_in[17];

  float* out = (float*)d_out;
  char* ws = (char*)d_ws;
  // Region A [0, 48MB): disjoint lifetimes per step:
  unsigned short* A0b  = (unsigned short*)(ws + 0);         // L1 gemm out 128ch bf16
  unsigned short* A1b  = (unsigned short*)(ws + 12800000);  // L2 gemm out 64ch bf16
  unsigned short* C2b  = (unsigned short*)(ws + 32000000);  // enc2 bf16 (L3 agg input)
  unsigned short* G3hi = (unsigned short*)(ws + 0);         // L3 agg out hi (6.4M)
  unsigned short* G3lo = (unsigned short*)(ws + 6400000);   // L3 agg out lo (6.4M)
  unsigned short* D3b  = (unsigned short*)(ws + 12800000);  // h3 bf16 (L4 agg input, 12.8M)
  unsigned short* G4hi = (unsigned short*)(ws + 0);         // L4 agg out hi (12.8M)
  unsigned short* G4lo = (unsigned short*)(ws + 25600000);  // L4 agg out lo (12.8M)
  unsigned short* Wb   = (unsigned short*)(ws + 48000000);  // weights, persist
  unsigned short* W1h = Wb;            unsigned short* W1l = W1h + 32768;
  unsigned short* W2h = W1l + 32768;   unsigned short* W2l = W2h + 8192;
  unsigned short* W3h = W2l + 8192;    unsigned short* W3l = W3h + 8192;
  unsigned short* W4h = W3l + 8192;    unsigned short* W4l = W4h + 32768;
  float* B0f  = (float*)(ws + 51200000);  // pre-BN fp32 (up to 51.2M at L4)
  int*   csrS   = (int*)(ws + 102400000);
  float* csrW   = (float*)(ws + 105600000);
  float* stat4  = (float*)(ws + 108800000);  // 4 x 512 floats (reuses counts region? no: counts below)
  int*   counts = (int*)(ws + 108810000);
  int*   cursor = (int*)(ws + 109010000);
  int*   offs   = (int*)(ws + 109210000);
  float* dinv   = (float*)(ws + 109410064);
  if (ws_size < 109604160) return;
  float* rowsum = (float*)cursor;  // reuse cursor region after fill_csr

  float* enc1 = out + (size_t)N_NODES * F0;
  float* enc2 = enc1 + (size_t)N_NODES * F1;

  const int EB = (E + 255) / 256;
  const int AGG_GRID = 2048;
  const int MB = (N_NODES + 127) / 128;  // 391

  // conversions + CSR build
  convert_weights<<<320, 256, 0, stream>>>(We1, We2, Wd1, Wd2, W1h, W1l, W2h, W2l,
                                           W3h, W3l, W4h, W4l);
  hipMemsetAsync(counts, 0, 2 * N_NODES * sizeof(int) + 20000, stream);  // counts+cursor
  hipMemsetAsync(stat4, 0, 4 * 512 * sizeof(float), stream);
  count_dst<<<EB, 256, 0, stream>>>(dst, counts, E);
  compute_dinv<<<(N_NODES + 255) / 256, 256, 0, stream>>>(counts, dinv);
  scan_offsets<<<1, 1024, 0, stream>>>(counts, offs);
  fill_csr<<<EB, 256, 0, stream>>>(src, dst, offs, cursor, dinv, csrS, csrW, E);
  compute_rowsum<<<(N_NODES + 255) / 256, 256, 0, stream>>>(offs, csrW, dinv, rowsum);

  // ---- Layer 1: F0 -> F1 (propagate after) ----
  mfma_gemm_split<128, false, true><<<dim3(MB, 1), 256, 0, stream>>>(
      nullptr, nullptr, x, W1h, W1l, be1, nullptr, A0b, nullptr, nullptr, N_NODES, F0, F1);
  agg128_rl<true, false><<<AGG_GRID, 256, 0, stream>>>(
      A0b, offs, csrS, csrW, dinv, B0f, nullptr, nullptr, stat4);
  bn_apply_f<F1, true, true, false, false><<<2048, 256, 0, stream>>>(
      B0f, stat4, g1, bb1, enc1, nullptr, nullptr, nullptr);

  // ---- Layer 2: F1 -> F2 (propagate after); GEMM reads enc1 fp32, splits in staging ----
  mfma_gemm_split<64, false, true><<<dim3(MB, 1), 256, 0, stream>>>(
      nullptr, nullptr, enc1, W2h, W2l, be2, nullptr, A1b, nullptr, nullptr, N_NODES, F1, F2);
  agg64_rl<true, false><<<AGG_GRID, 256, 0, stream>>>(
      A1b, offs, csrS, csrW, dinv, B0f, nullptr, nullptr, stat4 + 512);
  bn_apply_f<F2, false, true, true, false><<<2048, 256, 0, stream>>>(
      B0f, stat4 + 512, g2, bb2, enc2, C2b, nullptr, nullptr);

  // ---- Layer 3: F2 -> F1 (propagate FIRST) ----
  agg64_rl<false, true><<<AGG_GRID, 256, 0, stream>>>(
      C2b, offs, csrS, csrW, dinv, nullptr, G3hi, G3lo, nullptr);
  mfma_gemm_split<128, true, false><<<dim3(MB, 1), 256, 0, stream>>>(
      G3hi, G3lo, nullptr, W3h, W3l, bd1, rowsum, nullptr, B0f, stat4 + 1024, N_NODES, F2, F1);
  bn_apply_f<F1, true, false, true, false><<<2048, 256, 0, stream>>>(
      B0f, stat4 + 1024, g3, bb3, nullptr, D3b, nullptr, nullptr);

  // ---- Layer 4: F1 -> F0 (propagate FIRST) ----
  agg128_rl<false, true><<<AGG_GRID, 256, 0, stream>>>(
      D3b, offs, csrS, csrW, dinv, nullptr, G4hi, G4lo, nullptr);
  mfma_gemm_split<128, true, false><<<dim3(MB, 2), 256, 0, stream>>>(
      G4hi, G4lo, nullptr, W4h, W4l, bd2, rowsum, nullptr, B0f, stat4 + 1536, N_NODES, F1, F0);
  bn_apply_f<F0, false, true, false, false><<<2048, 256, 0, stream>>>(
      B0f, stat4 + 1536, g4, bb4, out, nullptr, nullptr, nullptr);
}